// Round 9
// baseline (3301.473 us; speedup 1.0000x reference)
//
#include <hip/hip_runtime.h>

typedef unsigned short u16;
typedef unsigned int u32;
typedef __attribute__((ext_vector_type(8))) short bf16x8_t;
typedef __attribute__((ext_vector_type(4))) float f32x4_t;

// problem constants
#define kN 65536
#define kE 262144
#define kG 2048
#define kH 300
#define kH2 600
#define kL 5
#define kF 32
#define kDG 1523
// padded dims
#define KP_H 320     // K pad of H (mult of 64)
#define KP_H2 640    // K pad of 2H
#define KP_DG 1536   // K pad of DG
#define NP_H2 640    // N pad of 2H
#define NP_H 384     // N pad of H
// hvbf row stride (u16 / u32)
#define HVS 320
#define HVS32 160

__device__ __forceinline__ float bf2f(u16 x) {
    union { u32 u; float f; } v; v.u = ((u32)x) << 16; return v.f;
}
__device__ __forceinline__ u16 f2bf(float f) {
    union { float f; u32 u; } v; v.f = f;
    u32 u = v.u;
    u32 r = (u + 0x7fffu + ((u >> 16) & 1u)) >> 16;  // RNE
    return (u16)r;
}
__device__ __forceinline__ float blo(u32 v) { return bf2f((u16)(v & 0xffffu)); }
__device__ __forceinline__ float bhi(u32 v) { return bf2f((u16)(v >> 16)); }
__device__ __forceinline__ u32 pack2(float lo, float hi) {
    return (u32)f2bf(lo) | ((u32)f2bf(hi) << 16);
}

// async 16B global -> LDS (wave-uniform lds base; lane writes base + lane*16)
__device__ __forceinline__ void gld16(const u16* g, u16* l) {
    __builtin_amdgcn_global_load_lds(
        (const __attribute__((address_space(1))) u32*)g,
        (__attribute__((address_space(3))) u32*)l, 16, 0, 0);
}

// ---------------- weight transpose: W[b][k][n] (f32) -> Wt[b][n][k] (bf16), zero-padded ----------------
__global__ void transpose_k(const float* __restrict__ W, u16* __restrict__ Wt,
                            int K, int NN, int NP, int KP, long total) {
    long idx = (long)blockIdx.x * 256 + threadIdx.x;
    if (idx >= total) return;
    int per = NP * KP;
    int b = (int)(idx / per);
    int r = (int)(idx % per);
    int n = r / KP;
    int k = r % KP;
    u16 v = 0;
    if (n < NN && k < K) v = f2bf(W[(long)b * K * NN + (long)k * NN + n]);
    Wt[idx] = v;
}

// ---------------- graph histogram + scan (G=2048) ----------------
__global__ void hist_g_k(const int* __restrict__ batch, int* __restrict__ counts) {
    int n = blockIdx.x * 256 + threadIdx.x;
    if (n < kN) atomicAdd(&counts[batch[n]], 1);
}

__global__ void scan_g_k(const int* __restrict__ counts, int* __restrict__ starts) {
    __shared__ int s[1024];
    int t = threadIdx.x;
    int c0 = counts[2 * t], c1 = counts[2 * t + 1];
    s[t] = c0 + c1;
    __syncthreads();
    for (int off = 1; off < 1024; off <<= 1) {
        int v = (t >= off) ? s[t - off] : 0;
        __syncthreads();
        s[t] += v;
        __syncthreads();
    }
    int excl = (t > 0) ? s[t - 1] : 0;
    starts[2 * t] = excl;
    starts[2 * t + 1] = excl + c0;
}

// ---------------- node CSR build (dst-sorted edges), 3-phase scan ----------------
__global__ void hist_n_k(const int* __restrict__ ei, int* __restrict__ cnt) {
    int e = blockIdx.x * 256 + threadIdx.x;
    if (e < kE) atomicAdd(&cnt[ei[kE + e]], 1);  // dst
}

__global__ void scanA_k(const int* __restrict__ cnt, int* __restrict__ start, int* __restrict__ bsum) {
    __shared__ int s[1024];
    int b = blockIdx.x, t = threadIdx.x;
    int v = cnt[b * 1024 + t];
    s[t] = v;
    __syncthreads();
    for (int off = 1; off < 1024; off <<= 1) {
        int u = (t >= off) ? s[t - off] : 0;
        __syncthreads();
        s[t] += u;
        __syncthreads();
    }
    start[b * 1024 + t] = s[t] - v;  // block-local exclusive
    if (t == 1023) bsum[b] = s[1023];
}

__global__ void scanB_k(int* __restrict__ bsum) {
    if (threadIdx.x == 0) {
        int s = 0;
        for (int i = 0; i < kN / 1024; i++) { s += bsum[i]; bsum[i] = s; }  // inclusive
    }
}

__global__ void scanC_k(int* __restrict__ start, const int* __restrict__ bsum) {
    int b = blockIdx.x, t = threadIdx.x;
    int add = (b > 0) ? bsum[b - 1] : 0;
    start[b * 1024 + t] += add;
    if (b == kN / 1024 - 1 && t == 1023) start[kN] = bsum[kN / 1024 - 1];
}

__global__ void fill_n_k(const int* __restrict__ ei, const int* __restrict__ start,
                         int* __restrict__ fill, int* __restrict__ perm) {
    int e = blockIdx.x * 256 + threadIdx.x;
    if (e >= kE) return;
    int s = ei[e], d = ei[kE + e];
    int pos = start[d] + atomicAdd(&fill[d], 1);
    perm[pos] = s;
}

// ---------------- node embedding (wave per node, u32 cols): hbf, hvbf ----------------
__global__ __launch_bounds__(256) void embed_k(
    const float* __restrict__ x, const float* __restrict__ W,
    const float* __restrict__ b, u32* __restrict__ hbf32,
    const float* __restrict__ vn0, u32* __restrict__ hv32) {
    int tid = threadIdx.x;
    int wave = tid >> 6, lane = tid & 63;
    int n = blockIdx.x * 4 + wave;
    float xv[9];
    #pragma unroll
    for (int d = 0; d < 9; d++) xv[d] = x[n * 9 + d];
    #pragma unroll
    for (int p = 0; p < 3; p++) {
        int ii = lane + p * 64;
        if (ii < 150) {
            int c0 = 2 * ii;
            float2 bb = *(const float2*)(b + c0);
            float a0 = bb.x, a1 = bb.y;
            #pragma unroll
            for (int d = 0; d < 9; d++) {
                float2 wv = *(const float2*)(W + d * kH + c0);
                a0 += xv[d] * wv.x;
                a1 += xv[d] * wv.y;
            }
            hbf32[(long)n * 150 + ii] = pack2(a0, a1);
            float2 vv = *(const float2*)(vn0 + c0);
            hv32[(long)n * HVS32 + ii] = pack2(a0 + vv.x, a1 + vv.y);
        } else if (ii < HVS32) {
            hv32[(long)n * HVS32 + ii] = 0u;
        }
    }
}

__global__ void vninit_k(const float* __restrict__ vn0, float* __restrict__ vn) {
    int g = blockIdx.x, c = threadIdx.x;
    if (c < kH) vn[g * kH + c] = vn0[c];
}

// ---------------- gather + combine: one WAVE per node, u32 (2-col) lanes ----------------
__global__ __launch_bounds__(256) void gather_combine_k(
    const u32* __restrict__ hv32, const int* __restrict__ start_n,
    const int* __restrict__ perm, const float* __restrict__ eps, int l,
    u32* __restrict__ out32, float* __restrict__ stats) {
    int tid = threadIdx.x;
    int wave = tid >> 6, lane = tid & 63;
    int n = blockIdx.x * 4 + wave;
    int st = start_n[n], en = start_n[n + 1];
    int i0 = lane, i1 = lane + 64, i2 = lane + 128;
    bool p2 = (i2 < 150);
    float a0 = 0.f, b0 = 0.f, a1 = 0.f, b1 = 0.f, a2 = 0.f, b2 = 0.f;
    int e = st;
    for (; e + 2 <= en; e += 2) {
        const u32* rA = hv32 + (long)perm[e] * HVS32;
        const u32* rB = hv32 + (long)perm[e + 1] * HVS32;
        u32 vA0 = rA[i0], vA1 = rA[i1], vA2 = p2 ? rA[i2] : 0u;
        u32 vB0 = rB[i0], vB1 = rB[i1], vB2 = p2 ? rB[i2] : 0u;
        a0 += blo(vA0) + blo(vB0); b0 += bhi(vA0) + bhi(vB0);
        a1 += blo(vA1) + blo(vB1); b1 += bhi(vA1) + bhi(vB1);
        a2 += blo(vA2) + blo(vB2); b2 += bhi(vA2) + bhi(vB2);
    }
    if (e < en) {
        const u32* rA = hv32 + (long)perm[e] * HVS32;
        u32 vA0 = rA[i0], vA1 = rA[i1], vA2 = p2 ? rA[i2] : 0u;
        a0 += blo(vA0); b0 += bhi(vA0);
        a1 += blo(vA1); b1 += bhi(vA1);
        a2 += blo(vA2); b2 += bhi(vA2);
    }
    const u32* self = hv32 + (long)n * HVS32;
    float ep = 1.f + eps[l];
    u32 s0 = self[i0], s1 = self[i1];
    u32* o = out32 + (long)n * HVS32;
    o[i0] = pack2(ep * blo(s0) + a0, ep * bhi(s0) + b0);
    o[i1] = pack2(ep * blo(s1) + a1, ep * bhi(s1) + b1);
    if (p2) {
        u32 s2 = self[i2];
        o[i2] = pack2(ep * blo(s2) + a2, ep * bhi(s2) + b2);
    } else if (i2 < HVS32) {
        o[i2] = 0u;  // K-pad cols 300..319
    }
    int gz = blockIdx.x * 256 + tid;
    if (gz < 2 * kH) stats[gz] = 0.f;
}

// ---------------- vt_in[g] = bf16(sum_{rows of g} hvbf + vn[g]) (contiguous rows) ----------------
__global__ void vt_fin_k(const u16* __restrict__ hvbf, const float* __restrict__ vn,
                         const int* __restrict__ counts, const int* __restrict__ starts,
                         u16* __restrict__ vt_in) {
    int g = blockIdx.x, c = threadIdx.x;  // 320
    if (c >= kH) { vt_in[(long)g * KP_H + c] = 0; return; }
    int cnt = counts[g], st = starts[g];
    float acc = vn[g * kH + c];
    for (int i = 0; i < cnt; i++) acc += bf2f(hvbf[(long)(st + i) * HVS + c]);
    vt_in[(long)g * KP_H + c] = f2bf(acc);
}

// ---------------- fused node MLP: z2 = relu(A@W1+b1)@W2 + b2, in place over A ----------------
// block = 256 (4 waves); each wave owns 16 rows, fully independent through both GEMMs.
// z1 stripe lives in per-wave LDS (C-layout write -> A-layout read), never touches HBM.
__global__ __launch_bounds__(256) void mlp_fused_k(
    const u16* __restrict__ W1t,    // [640][320] bf16 (n-major)
    const float* __restrict__ b1,   // [600]
    const u16* __restrict__ W2t,    // [384][640] bf16
    const float* __restrict__ b2,   // [300]
    u16* __restrict__ AZ,           // [kN][320] bf16: A in, z2 out (in place)
    float* __restrict__ stats) {
    __shared__ __align__(16) u16 z1s[4][16][328];  // stride 328 -> 2-way bank aliasing only
    __shared__ float sred[320][2];

    const int tid = threadIdx.x;
    const int lane = tid & 63;
    const int wave = tid >> 6;
    const int l16 = lane & 15;
    const int q = lane >> 4;
    const long tm = (long)blockIdx.x * 64 + wave * 16;

    for (int i = tid; i < 320; i += 256) { sred[i][0] = 0.f; sred[i][1] = 0.f; }
    __syncthreads();

    f32x4_t acc2[24];
    #pragma unroll
    for (int i = 0; i < 24; i++) acc2[i] = (f32x4_t){0.f, 0.f, 0.f, 0.f};

    const u16* Arow = AZ + (tm + l16) * KP_H;  // A-fragment row for this lane

    #pragma unroll
    for (int hh = 0; hh < 2; hh++) {
        // ---- phase 1: z1 cols [hh*320, hh*320+320) in two 160-col chunks ----
        #pragma unroll
        for (int nq = 0; nq < 2; nq++) {
            f32x4_t a1[10];
            #pragma unroll
            for (int i = 0; i < 10; i++) a1[i] = (f32x4_t){0.f, 0.f, 0.f, 0.f};
            #pragma unroll
            for (int ks = 0; ks < 10; ks++) {
                bf16x8_t av = *(const bf16x8_t*)(Arow + ks * 32 + q * 8);
                #pragma unroll
                for (int nt = 0; nt < 10; nt++) {
                    int n = hh * 320 + nq * 160 + nt * 16 + l16;
                    bf16x8_t bv = *(const bf16x8_t*)(W1t + (long)n * KP_H + ks * 32 + q * 8);
                    a1[nt] = __builtin_amdgcn_mfma_f32_16x16x32_bf16(av, bv, a1[nt], 0, 0, 0);
                }
            }
            #pragma unroll
            for (int nt = 0; nt < 10; nt++) {
                int ncol = nq * 160 + nt * 16 + l16;
                int gcol = hh * 320 + ncol;
                float b1v = (gcol < kH2) ? b1[gcol] : 0.f;
                #pragma unroll
                for (int r = 0; r < 4; r++) {
                    float v = fmaxf(a1[nt][r] + b1v, 0.f);
                    z1s[wave][q * 4 + r][ncol] = f2bf(v);
                }
            }
        }
        // ---- phase 2 partial: K chunk [hh*320, +320) of z1 ----
        #pragma unroll
        for (int ks = 0; ks < 10; ks++) {
            bf16x8_t av = *(const bf16x8_t*)&z1s[wave][l16][ks * 32 + q * 8];
            #pragma unroll
            for (int nt = 0; nt < 24; nt++) {
                int n = nt * 16 + l16;
                bf16x8_t bv = *(const bf16x8_t*)(W2t + (long)n * KP_H2 + hh * 320 + ks * 32 + q * 8);
                acc2[nt] = __builtin_amdgcn_mfma_f32_16x16x32_bf16(av, bv, acc2[nt], 0, 0, 0);
            }
        }
    }

    // ---- epilogue: bias, store z2 (in place), BN stats ----
    #pragma unroll
    for (int nt = 0; nt < 24; nt++) {
        int col = nt * 16 + l16;
        float bv = (col < kH) ? b2[col] : 0.f;
        float s = 0.f, s2 = 0.f;
        #pragma unroll
        for (int r = 0; r < 4; r++) {
            float v = acc2[nt][r] + bv;
            float sv = (col < kH) ? v : 0.f;
            if (col < KP_H) AZ[(tm + q * 4 + r) * KP_H + col] = f2bf(sv);
            s += sv; s2 += sv * sv;
        }
        if (col < kH) {
            atomicAdd(&sred[col][0], s);
            atomicAdd(&sred[col][1], s2);
        }
    }
    __syncthreads();
    // FIX (round 8 bug): strided flush — block has 256 threads but kH=300 columns;
    // the old `if (tid < kH)` left cols 256..299 un-flushed -> var=0 -> blow-up.
    for (int i = tid; i < kH; i += 256) {
        atomicAdd(&stats[i], sred[i][0]);
        atomicAdd(&stats[kH + i], sred[i][1]);
    }
}

// ---------------- GEMM (vn path + predictor): 128x128 tile, BK=64, global_load_lds ----------------
template<int ACT, int OUT_BF16>
__global__ __launch_bounds__(256) void gemm_k(
    const u16* __restrict__ A, const u16* __restrict__ Wt,
    const float* __restrict__ bias, void* __restrict__ out,
    int KP, int NN, int out_stride, int store_cols) {
    __shared__ __align__(16) u16 lA[128 * 64];
    __shared__ __align__(16) u16 lB[128 * 64];

    const int tid = threadIdx.x;
    const int lane = tid & 63;
    const int wave = tid >> 6;
    const int l16 = lane & 15;
    const int quad = lane >> 4;
    const int wm = (wave & 1) * 64;
    const int wn = (wave >> 1) * 64;
    const long tm = (long)blockIdx.x * 128;
    const int tn = blockIdx.y * 128;

    const int srow = lane >> 3;            // 0..7
    const int sch = (lane & 7) ^ srow;     // XOR-swizzled logical k-chunk

    f32x4_t acc[4][4];
    #pragma unroll
    for (int i = 0; i < 4; i++)
        #pragma unroll
        for (int j = 0; j < 4; j++) acc[i][j] = (f32x4_t){0.f, 0.f, 0.f, 0.f};

    for (int k0 = 0; k0 < KP; k0 += 64) {
        __syncthreads();
        #pragma unroll
        for (int j = 0; j < 4; j++) {
            int rb = wave * 32 + j * 8;          // wave-uniform base row
            int r = rb + srow;                   // r & 7 == srow
            gld16(A + (tm + r) * KP + k0 + sch * 8, &lA[rb * 64]);
            gld16(Wt + (long)(tn + r) * KP + k0 + sch * 8, &lB[rb * 64]);
        }
        __syncthreads();
        #pragma unroll
        for (int ks = 0; ks < 2; ks++) {
            bf16x8_t af[4], bfr[4];
            #pragma unroll
            for (int mt = 0; mt < 4; mt++) {
                int row = wm + mt * 16 + l16;
                int phys = (ks * 4 + quad) ^ (l16 & 7);
                af[mt] = *(const bf16x8_t*)&lA[row * 64 + phys * 8];
            }
            #pragma unroll
            for (int nt = 0; nt < 4; nt++) {
                int row = wn + nt * 16 + l16;
                int phys = (ks * 4 + quad) ^ (l16 & 7);
                bfr[nt] = *(const bf16x8_t*)&lB[row * 64 + phys * 8];
            }
            #pragma unroll
            for (int mt = 0; mt < 4; mt++)
                #pragma unroll
                for (int nt = 0; nt < 4; nt++)
                    acc[mt][nt] = __builtin_amdgcn_mfma_f32_16x16x32_bf16(af[mt], bfr[nt], acc[mt][nt], 0, 0, 0);
        }
    }

    #pragma unroll
    for (int nt = 0; nt < 4; nt++) {
        int col = tn + wn + nt * 16 + l16;
        float bv = (col < NN) ? bias[col] : 0.f;
        #pragma unroll
        for (int mt = 0; mt < 4; mt++) {
            #pragma unroll
            for (int r = 0; r < 4; r++) {
                long row = tm + wm + mt * 16 + quad * 4 + r;
                float v = acc[mt][nt][r] + bv;
                if (ACT) v = fmaxf(v, 0.f);
                float sv = (col < NN) ? v : 0.f;
                if (col < store_cols) {
                    if (OUT_BF16) ((u16*)out)[row * out_stride + col] = f2bf(sv);
                    else          ((float*)out)[row * out_stride + col] = sv;
                }
            }
        }
    }
}

// ---------------- BN-apply + (relu) + residual (wave per node, u32 cols) ----------------
template<int RELU, int WRITE_HV>
__global__ __launch_bounds__(256) void resid_k(
    u32* __restrict__ hbf32, u32* __restrict__ hv32,
    const u32* __restrict__ z32, const float* __restrict__ stats,
    const float* __restrict__ scale, const float* __restrict__ bias, int l,
    const int* __restrict__ batch, const float* __restrict__ vn) {
    int tid = threadIdx.x;
    int wave = tid >> 6, lane = tid & 63;
    int n = blockIdx.x * 4 + wave;
    int g = WRITE_HV ? batch[n] : 0;
    #pragma unroll
    for (int p = 0; p < 3; p++) {
        int ii = lane + p * 64;
        if (ii >= 150) break;
        int c0 = 2 * ii;
        float m0 = stats[c0] * (1.f / (float)kN), m1 = stats[c0 + 1] * (1.f / (float)kN);
        float v0 = fmaxf(stats[kH + c0] * (1.f / (float)kN) - m0 * m0, 0.f);
        float v1 = fmaxf(stats[kH + c0 + 1] * (1.f / (float)kN) - m1 * m1, 0.f);
        float a0 = scale[l * kH + c0] * rsqrtf(v0 + 1e-5f);
        float a1 = scale[l * kH + c0 + 1] * rsqrtf(v1 + 1e-5f);
        float d0 = bias[l * kH + c0] - m0 * a0;
        float d1 = bias[l * kH + c0 + 1] - m1 * a1;
        u32 zz = z32[(long)n * HVS32 + ii];
        u32 hh = hbf32[(long)n * 150 + ii];
        float t0 = blo(zz) * a0 + d0;
        float t1 = bhi(zz) * a1 + d1;
        if (RELU) { t0 = fmaxf(t0, 0.f); t1 = fmaxf(t1, 0.f); }
        float h0 = blo(hh) + t0, h1 = bhi(hh) + t1;
        hbf32[(long)n * 150 + ii] = pack2(h0, h1);
        if (WRITE_HV) {
            float2 vv = *(const float2*)(vn + g * kH + c0);
            hv32[(long)n * HVS32 + ii] = pack2(h0 + vv.x, h1 + vv.y);
        }
    }
}

__global__ void vnupd_k(float* __restrict__ vn, const float* __restrict__ z) {
    int g = blockIdx.x, c = threadIdx.x;
    if (c < kH) vn[g * kH + c] += fmaxf(z[g * kH + c], 0.f);
}

// ---------------- h_rep cols [0,300): pooled mean of hbf (contiguous rows) ----------------
__global__ void pooled_k(const u16* __restrict__ hbf, const int* __restrict__ counts,
                         const int* __restrict__ starts, u16* __restrict__ hrep) {
    int g = blockIdx.x, c = threadIdx.x;
    if (c >= kH) return;
    int cnt = counts[g], st = starts[g];
    float acc = 0.f;
    for (int i = 0; i < cnt; i++) acc += bf2f(hbf[(long)(st + i) * kH + c]);
    acc /= (float)(cnt > 0 ? cnt : 1);
    hrep[(long)g * KP_DG + c] = f2bf(acc);
}

// ---------------- h_rep cols [300,1536): id_pool | morgan | maccs | zero-pad ----------------
__global__ void hrep_rest_k(const float* __restrict__ morgan, const float* __restrict__ maccs,
                            const int* __restrict__ counts, u16* __restrict__ hrep) {
    long idx = (long)blockIdx.x * 256 + threadIdx.x;
    if (idx >= (long)kG * (KP_DG - kH)) return;
    int g = (int)(idx / (KP_DG - kH));
    int j = (int)(idx % (KP_DG - kH));
    int col = kH + j;
    u16 v;
    if (j < kF) {
        int c = counts[g];
        int q = (j < c) ? ((c - 1 - j) / kF + 1) : 0;  // #k in [0,c) with k%32==j
        v = f2bf((float)q / (float)(c > 0 ? c : 1));
    } else if (j < kF + 1024) {
        v = f2bf(morgan[(long)g * 1024 + (j - kF)]);
    } else if (j < kF + 1024 + 167) {
        v = f2bf(maccs[(long)g * 167 + (j - kF - 1024)]);
    } else {
        v = 0;
    }
    hrep[(long)g * KP_DG + col] = v;
}

// ---------------- final: out[g] = zp[g,:600] . Wp2 + bp2 ----------------
__global__ void final_k(const u16* __restrict__ zp, const float* __restrict__ Wp2,
                        const float* __restrict__ bp2, float* __restrict__ out) {
    int wave = threadIdx.x >> 6, lane = threadIdx.x & 63;
    int g = blockIdx.x * 4 + wave;
    float acc = 0.f;
    for (int c = lane; c < kH2; c += 64) acc += bf2f(zp[(long)g * KP_H2 + c]) * Wp2[c];
    #pragma unroll
    for (int off = 32; off; off >>= 1) acc += __shfl_down(acc, off);
    if (lane == 0) out[g] = acc + bp2[0];
}

extern "C" void kernel_launch(void* const* d_in, const int* in_sizes, int n_in,
                              void* d_out, int out_size, void* d_ws, size_t ws_size,
                              hipStream_t stream) {
    const float* x      = (const float*)d_in[0];
    const float* morgan = (const float*)d_in[1];
    const float* maccs  = (const float*)d_in[2];
    const int*   ei     = (const int*)d_in[3];
    const int*   batch  = (const int*)d_in[4];
    const float* W_emb  = (const float*)d_in[5];
    const float* b_emb  = (const float*)d_in[6];
    const float* gin_W1 = (const float*)d_in[7];
    const float* gin_b1 = (const float*)d_in[8];
    const float* gin_W2 = (const float*)d_in[9];
    const float* gin_b2 = (const float*)d_in[10];
    const float* bn_scale = (const float*)d_in[11];
    const float* bn_bias  = (const float*)d_in[12];
    const float* eps    = (const float*)d_in[13];
    const float* vn0    = (const float*)d_in[14];
    const float* vn_W1  = (const float*)d_in[15];
    const float* vn_b1  = (const float*)d_in[16];
    const float* vn_W2  = (const float*)d_in[17];
    const float* vn_b2  = (const float*)d_in[18];
    const float* Wp1    = (const float*)d_in[19];
    const float* bp1    = (const float*)d_in[20];
    const float* Wp2    = (const float*)d_in[21];
    const float* bp2    = (const float*)d_in[22];
    float* out = (float*)d_out;

    char* ws = (char*)d_ws;
    size_t off = 0;
    auto alloc = [&](size_t bytes) -> char* {
        char* p = ws + off;
        off += (bytes + 255) & ~(size_t)255;
        return p;
    };
    u16*   hbf  = (u16*)alloc((size_t)kN * kH * 2);         // 39.3 MB bf16 h
    u16*   hvbf = (u16*)alloc((size_t)kN * HVS * 2);        // 41.9 MB bf16(h+vn[batch]), padded
    u16*   hv   = (u16*)alloc((size_t)kN * KP_H * 2);       // 41.9 MB (hv_in -> z2, in place)
    char*  S    = alloc((size_t)10 * 1024 * 1024);          // 10 MB scratch region
    float* vn   = (float*)alloc((size_t)kG * kH * 4);       // 2.5 MB
    int* counts = (int*)alloc(kG * 4);
    int* starts = (int*)alloc(kG * 4);
    float* stats = (float*)alloc(2 * kH * 4);
    int* cnt_n  = (int*)alloc((size_t)kN * 4);
    int* start_n = (int*)alloc((size_t)(kN + 1) * 4);
    int* fill_n = (int*)alloc((size_t)kN * 4);
    int* bsum   = (int*)alloc((kN / 1024) * 4);
    int* perm   = (int*)alloc((size_t)kE * 4);
    u16* Wt_g1 = (u16*)alloc((size_t)kL * NP_H2 * KP_H * 2);
    u16* Wt_g2 = (u16*)alloc((size_t)kL * NP_H * KP_H2 * 2);
    u16* Wt_v1 = (u16*)alloc((size_t)(kL - 1) * NP_H2 * KP_H * 2);
    u16* Wt_v2 = (u16*)alloc((size_t)(kL - 1) * NP_H * KP_H2 * 2);
    u16* Wt_p1 = (u16*)alloc((size_t)NP_H2 * KP_DG * 2);
    if (off > ws_size) return;  // ~155 MB required

    // scratch-region overlays (disjoint lifetimes):
    u16*   vt_in = (u16*)S;                                        // [2048, 320] bf16
    u16*   z1v   = (u16*)(S + (size_t)kG * KP_H * 2);              // [2048, 640] bf16
    float* z2v   = (float*)(S + (size_t)kG * (KP_H + KP_H2) * 2);  // [2048, 300] f32
    u16*   hrep  = (u16*)S;                                        // [2048, 1536] bf16 (post-layers)
    u16*   zp    = (u16*)(S + (size_t)kG * KP_DG * 2);             // [2048, 640] bf16

    // weight transposes (f32 -> padded bf16)
    {
        long t1 = (long)kL * NP_H2 * KP_H;
        transpose_k<<<dim3((unsigned)((t1 + 255) / 256)), 256, 0, stream>>>(gin_W1, Wt_g1, kH, kH2, NP_H2, KP_H, t1);
        long t2 = (long)kL * NP_H * KP_H2;
        transpose_k<<<dim3((unsigned)((t2 + 255) / 256)), 256, 0, stream>>>(gin_W2, Wt_g2, kH2, kH, NP_H, KP_H2, t2);
        long t3 = (long)(kL - 1) * NP_H2 * KP_H;
        transpose_k<<<dim3((unsigned)((t3 + 255) / 256)), 256, 0, stream>>>(vn_W1, Wt_v1, kH, kH2, NP_H2, KP_H, t3);
        long t4 = (long)(kL - 1) * NP_H * KP_H2;
        transpose_k<<<dim3((unsigned)((t4 + 255) / 256)), 256, 0, stream>>>(vn_W2, Wt_v2, kH2, kH, NP_H, KP_H2, t4);
        long t5 = (long)NP_H2 * KP_DG;
        transpose_k<<<dim3((unsigned)((t5 + 255) / 256)), 256, 0, stream>>>(Wp1, Wt_p1, kDG, kH2, NP_H2, KP_DG, t5);
    }

    // graph ranges + node CSR
    hipMemsetAsync(counts, 0, kG * 4, stream);
    hipMemsetAsync(cnt_n, 0, (size_t)kN * 4, stream);
    hipMemsetAsync(fill_n, 0, (size_t)kN * 4, stream);
    hist_g_k<<<kN / 256, 256, 0, stream>>>(batch, counts);
    scan_g_k<<<1, 1024, 0, stream>>>(counts, starts);
    hist_n_k<<<kE / 256, 256, 0, stream>>>(ei, cnt_n);
    scanA_k<<<kN / 1024, 1024, 0, stream>>>(cnt_n, start_n, bsum);
    scanB_k<<<1, 64, 0, stream>>>(bsum);
    scanC_k<<<kN / 1024, 1024, 0, stream>>>(start_n, bsum);
    fill_n_k<<<kE / 256, 256, 0, stream>>>(ei, start_n, fill_n, perm);

    embed_k<<<kN / 4, 256, 0, stream>>>(x, W_emb, b_emb, (u32*)hbf, vn0, (u32*)hvbf);
    vninit_k<<<kG, 320, 0, stream>>>(vn0, vn);

    for (int l = 0; l < kL; l++) {
        gather_combine_k<<<kN / 4, 256, 0, stream>>>(
            (const u32*)hvbf, start_n, perm, eps, l, (u32*)hv, stats);
        if (l < kL - 1) {
            vt_fin_k<<<kG, 320, 0, stream>>>(hvbf, vn, counts, starts, vt_in);
            gemm_k<1, 1><<<dim3(16, NP_H2 / 128), 256, 0, stream>>>(
                vt_in, Wt_v1 + (size_t)l * NP_H2 * KP_H, vn_b1 + l * kH2,
                z1v, KP_H, kH2, KP_H2, KP_H2);
            gemm_k<0, 0><<<dim3(16, NP_H / 128), 256, 0, stream>>>(
                z1v, Wt_v2 + (size_t)l * NP_H * KP_H2, vn_b2 + l * kH,
                z2v, KP_H2, kH, kH, kH);
            vnupd_k<<<kG, 320, 0, stream>>>(vn, z2v);  // vn becomes vn_{l+1}
        }
        // fused node MLP: hv -> z2 (in place), BN stats accumulated
        mlp_fused_k<<<kN / 64, 256, 0, stream>>>(
            Wt_g1 + (size_t)l * NP_H2 * KP_H, gin_b1 + l * kH2,
            Wt_g2 + (size_t)l * NP_H * KP_H2, gin_b2 + l * kH,
            hv, stats);
        if (l < kL - 1)
            resid_k<1, 1><<<kN / 4, 256, 0, stream>>>(
                (u32*)hbf, (u32*)hvbf, (const u32*)hv, stats, bn_scale, bn_bias, l, batch, vn);
        else
            resid_k<0, 0><<<kN / 4, 256, 0, stream>>>(
                (u32*)hbf, (u32*)hvbf, (const u32*)hv, stats, bn_scale, bn_bias, l, batch, vn);
    }

    pooled_k<<<kG, 320, 0, stream>>>(hbf, counts, starts, hrep);
    {
        long tr = (long)kG * (KP_DG - kH);
        hrep_rest_k<<<dim3((unsigned)((tr + 255) / 256)), 256, 0, stream>>>(morgan, maccs, counts, hrep);
    }
    gemm_k<1, 1><<<dim3(16, NP_H2 / 128), 256, 0, stream>>>(
        hrep, Wt_p1, bp1, zp, KP_DG, kH2, KP_H2, KP_H2);
    final_k<<<kG / 4, 256, 0, stream>>>(zp, Wp2, bp2, out);
}

// Round 10
// 1535.693 us; speedup vs baseline: 2.1498x; 2.1498x over previous
//
#include <hip/hip_runtime.h>

typedef unsigned short u16;
typedef unsigned int u32;
typedef __attribute__((ext_vector_type(8))) short bf16x8_t;
typedef __attribute__((ext_vector_type(4))) float f32x4_t;

// problem constants
#define kN 65536
#define kE 262144
#define kG 2048
#define kH 300
#define kH2 600
#define kL 5
#define kF 32
#define kDG 1523
// padded dims
#define KP_H 320     // K pad of H (mult of 64)
#define KP_H2 640    // K pad of 2H
#define KP_DG 1536   // K pad of DG
#define NP_H2 640    // N pad of 2H
#define NP_H 384     // N pad of H
// M-chunking for node MLP
#define C_CHUNK 2
#define C_ROWS (kN / C_CHUNK)   // 32768
// hvbf row stride (u16 / u32)
#define HVS 320
#define HVS32 160

__device__ __forceinline__ float bf2f(u16 x) {
    union { u32 u; float f; } v; v.u = ((u32)x) << 16; return v.f;
}
__device__ __forceinline__ u16 f2bf(float f) {
    union { float f; u32 u; } v; v.f = f;
    u32 u = v.u;
    u32 r = (u + 0x7fffu + ((u >> 16) & 1u)) >> 16;  // RNE
    return (u16)r;
}
__device__ __forceinline__ float blo(u32 v) { return bf2f((u16)(v & 0xffffu)); }
__device__ __forceinline__ float bhi(u32 v) { return bf2f((u16)(v >> 16)); }
__device__ __forceinline__ u32 pack2(float lo, float hi) {
    return (u32)f2bf(lo) | ((u32)f2bf(hi) << 16);
}

// async 16B global -> LDS (wave-uniform lds base; lane writes base + lane*16)
__device__ __forceinline__ void gld16(const u16* g, u16* l) {
    __builtin_amdgcn_global_load_lds(
        (const __attribute__((address_space(1))) u32*)g,
        (__attribute__((address_space(3))) u32*)l, 16, 0, 0);
}

// ---------------- weight transpose: W[b][k][n] (f32) -> Wt[b][n][k] (bf16), zero-padded ----------------
__global__ void transpose_k(const float* __restrict__ W, u16* __restrict__ Wt,
                            int K, int NN, int NP, int KP, long total) {
    long idx = (long)blockIdx.x * 256 + threadIdx.x;
    if (idx >= total) return;
    int per = NP * KP;
    int b = (int)(idx / per);
    int r = (int)(idx % per);
    int n = r / KP;
    int k = r % KP;
    u16 v = 0;
    if (n < NN && k < K) v = f2bf(W[(long)b * K * NN + (long)k * NN + n]);
    Wt[idx] = v;
}

// ---------------- graph histogram + scan (G=2048) ----------------
__global__ void hist_g_k(const int* __restrict__ batch, int* __restrict__ counts) {
    int n = blockIdx.x * 256 + threadIdx.x;
    if (n < kN) atomicAdd(&counts[batch[n]], 1);
}

__global__ void scan_g_k(const int* __restrict__ counts, int* __restrict__ starts) {
    __shared__ int s[1024];
    int t = threadIdx.x;
    int c0 = counts[2 * t], c1 = counts[2 * t + 1];
    s[t] = c0 + c1;
    __syncthreads();
    for (int off = 1; off < 1024; off <<= 1) {
        int v = (t >= off) ? s[t - off] : 0;
        __syncthreads();
        s[t] += v;
        __syncthreads();
    }
    int excl = (t > 0) ? s[t - 1] : 0;
    starts[2 * t] = excl;
    starts[2 * t + 1] = excl + c0;
}

// ---------------- node CSR build (dst-sorted edges), 3-phase scan ----------------
__global__ void hist_n_k(const int* __restrict__ ei, int* __restrict__ cnt) {
    int e = blockIdx.x * 256 + threadIdx.x;
    if (e < kE) atomicAdd(&cnt[ei[kE + e]], 1);  // dst
}

__global__ void scanA_k(const int* __restrict__ cnt, int* __restrict__ start, int* __restrict__ bsum) {
    __shared__ int s[1024];
    int b = blockIdx.x, t = threadIdx.x;
    int v = cnt[b * 1024 + t];
    s[t] = v;
    __syncthreads();
    for (int off = 1; off < 1024; off <<= 1) {
        int u = (t >= off) ? s[t - off] : 0;
        __syncthreads();
        s[t] += u;
        __syncthreads();
    }
    start[b * 1024 + t] = s[t] - v;  // block-local exclusive
    if (t == 1023) bsum[b] = s[1023];
}

__global__ void scanB_k(int* __restrict__ bsum) {
    if (threadIdx.x == 0) {
        int s = 0;
        for (int i = 0; i < kN / 1024; i++) { s += bsum[i]; bsum[i] = s; }  // inclusive
    }
}

__global__ void scanC_k(int* __restrict__ start, const int* __restrict__ bsum) {
    int b = blockIdx.x, t = threadIdx.x;
    int add = (b > 0) ? bsum[b - 1] : 0;
    start[b * 1024 + t] += add;
    if (b == kN / 1024 - 1 && t == 1023) start[kN] = bsum[kN / 1024 - 1];
}

__global__ void fill_n_k(const int* __restrict__ ei, const int* __restrict__ start,
                         int* __restrict__ fill, int* __restrict__ perm) {
    int e = blockIdx.x * 256 + threadIdx.x;
    if (e >= kE) return;
    int s = ei[e], d = ei[kE + e];
    int pos = start[d] + atomicAdd(&fill[d], 1);
    perm[pos] = s;
}

// ---------------- node embedding (wave per node, u32 cols): hbf, hvbf ----------------
__global__ __launch_bounds__(256) void embed_k(
    const float* __restrict__ x, const float* __restrict__ W,
    const float* __restrict__ b, u32* __restrict__ hbf32,
    const float* __restrict__ vn0, u32* __restrict__ hv32) {
    int tid = threadIdx.x;
    int wave = tid >> 6, lane = tid & 63;
    int n = blockIdx.x * 4 + wave;
    float xv[9];
    #pragma unroll
    for (int d = 0; d < 9; d++) xv[d] = x[n * 9 + d];
    #pragma unroll
    for (int p = 0; p < 3; p++) {
        int ii = lane + p * 64;
        if (ii < 150) {
            int c0 = 2 * ii;
            float2 bb = *(const float2*)(b + c0);
            float a0 = bb.x, a1 = bb.y;
            #pragma unroll
            for (int d = 0; d < 9; d++) {
                float2 wv = *(const float2*)(W + d * kH + c0);
                a0 += xv[d] * wv.x;
                a1 += xv[d] * wv.y;
            }
            hbf32[(long)n * 150 + ii] = pack2(a0, a1);
            float2 vv = *(const float2*)(vn0 + c0);
            hv32[(long)n * HVS32 + ii] = pack2(a0 + vv.x, a1 + vv.y);
        } else if (ii < HVS32) {
            hv32[(long)n * HVS32 + ii] = 0u;
        }
    }
}

__global__ void vninit_k(const float* __restrict__ vn0, float* __restrict__ vn) {
    int g = blockIdx.x, c = threadIdx.x;
    if (c < kH) vn[g * kH + c] = vn0[c];
}

// ---------------- gather + combine: one WAVE per node, u32 (2-col) lanes ----------------
__global__ __launch_bounds__(256) void gather_combine_k(
    const u32* __restrict__ hv32, const int* __restrict__ start_n,
    const int* __restrict__ perm, const float* __restrict__ eps, int l,
    u32* __restrict__ out32, float* __restrict__ stats) {
    int tid = threadIdx.x;
    int wave = tid >> 6, lane = tid & 63;
    int n = blockIdx.x * 4 + wave;
    int st = start_n[n], en = start_n[n + 1];
    int i0 = lane, i1 = lane + 64, i2 = lane + 128;
    bool p2 = (i2 < 150);
    float a0 = 0.f, b0 = 0.f, a1 = 0.f, b1 = 0.f, a2 = 0.f, b2 = 0.f;
    int e = st;
    for (; e + 2 <= en; e += 2) {
        const u32* rA = hv32 + (long)perm[e] * HVS32;
        const u32* rB = hv32 + (long)perm[e + 1] * HVS32;
        u32 vA0 = rA[i0], vA1 = rA[i1], vA2 = p2 ? rA[i2] : 0u;
        u32 vB0 = rB[i0], vB1 = rB[i1], vB2 = p2 ? rB[i2] : 0u;
        a0 += blo(vA0) + blo(vB0); b0 += bhi(vA0) + bhi(vB0);
        a1 += blo(vA1) + blo(vB1); b1 += bhi(vA1) + bhi(vB1);
        a2 += blo(vA2) + blo(vB2); b2 += bhi(vA2) + bhi(vB2);
    }
    if (e < en) {
        const u32* rA = hv32 + (long)perm[e] * HVS32;
        u32 vA0 = rA[i0], vA1 = rA[i1], vA2 = p2 ? rA[i2] : 0u;
        a0 += blo(vA0); b0 += bhi(vA0);
        a1 += blo(vA1); b1 += bhi(vA1);
        a2 += blo(vA2); b2 += bhi(vA2);
    }
    const u32* self = hv32 + (long)n * HVS32;
    float ep = 1.f + eps[l];
    u32 s0 = self[i0], s1 = self[i1];
    u32* o = out32 + (long)n * HVS32;
    o[i0] = pack2(ep * blo(s0) + a0, ep * bhi(s0) + b0);
    o[i1] = pack2(ep * blo(s1) + a1, ep * bhi(s1) + b1);
    if (p2) {
        u32 s2 = self[i2];
        o[i2] = pack2(ep * blo(s2) + a2, ep * bhi(s2) + b2);
    } else if (i2 < HVS32) {
        o[i2] = 0u;  // K-pad cols 300..319
    }
    int gz = blockIdx.x * 256 + tid;
    if (gz < 2 * kH) stats[gz] = 0.f;
}

// ---------------- vt_in[g] = bf16(sum_{rows of g} hvbf + vn[g]) (contiguous rows) ----------------
__global__ void vt_fin_k(const u16* __restrict__ hvbf, const float* __restrict__ vn,
                         const int* __restrict__ counts, const int* __restrict__ starts,
                         u16* __restrict__ vt_in) {
    int g = blockIdx.x, c = threadIdx.x;  // 320
    if (c >= kH) { vt_in[(long)g * KP_H + c] = 0; return; }
    int cnt = counts[g], st = starts[g];
    float acc = vn[g * kH + c];
    for (int i = 0; i < cnt; i++) acc += bf2f(hvbf[(long)(st + i) * HVS + c]);
    vt_in[(long)g * KP_H + c] = f2bf(acc);
}

// ---------------- GEMM: 128x128 tile, BK=64, global_load_lds + XOR-swizzled LDS ----------------
// A: bf16 [M][KP] (zero K-pad). Wt: bf16 [NP][KP] rows (zero-padded). M%128==0, grid.y*128<=NP.
template<int ACT, int OUT_BF16, int BN_STATS>
__global__ __launch_bounds__(256) void gemm_k(
    const u16* __restrict__ A, const u16* __restrict__ Wt,
    const float* __restrict__ bias, void* __restrict__ out,
    float* __restrict__ stats,
    int KP, int NN, int out_stride, int store_cols) {
    __shared__ __align__(16) u16 lA[128 * 64];
    __shared__ __align__(16) u16 lB[128 * 64];
    __shared__ float sred[128][2];

    const int tid = threadIdx.x;
    const int lane = tid & 63;
    const int wave = tid >> 6;
    const int l16 = lane & 15;
    const int quad = lane >> 4;
    const int wm = (wave & 1) * 64;
    const int wn = (wave >> 1) * 64;
    const long tm = (long)blockIdx.x * 128;
    const int tn = blockIdx.y * 128;

    const int srow = lane >> 3;            // 0..7
    const int sch = (lane & 7) ^ srow;     // XOR-swizzled logical k-chunk

    f32x4_t acc[4][4];
    #pragma unroll
    for (int i = 0; i < 4; i++)
        #pragma unroll
        for (int j = 0; j < 4; j++) acc[i][j] = (f32x4_t){0.f, 0.f, 0.f, 0.f};

    for (int k0 = 0; k0 < KP; k0 += 64) {
        __syncthreads();
        #pragma unroll
        for (int j = 0; j < 4; j++) {
            int rb = wave * 32 + j * 8;          // wave-uniform base row
            int r = rb + srow;                   // r & 7 == srow
            gld16(A + (tm + r) * KP + k0 + sch * 8, &lA[rb * 64]);
            gld16(Wt + (long)(tn + r) * KP + k0 + sch * 8, &lB[rb * 64]);
        }
        __syncthreads();
        #pragma unroll
        for (int ks = 0; ks < 2; ks++) {
            bf16x8_t af[4], bfr[4];
            #pragma unroll
            for (int mt = 0; mt < 4; mt++) {
                int row = wm + mt * 16 + l16;
                int phys = (ks * 4 + quad) ^ (l16 & 7);
                af[mt] = *(const bf16x8_t*)&lA[row * 64 + phys * 8];
            }
            #pragma unroll
            for (int nt = 0; nt < 4; nt++) {
                int row = wn + nt * 16 + l16;
                int phys = (ks * 4 + quad) ^ (l16 & 7);
                bfr[nt] = *(const bf16x8_t*)&lB[row * 64 + phys * 8];
            }
            #pragma unroll
            for (int mt = 0; mt < 4; mt++)
                #pragma unroll
                for (int nt = 0; nt < 4; nt++)
                    acc[mt][nt] = __builtin_amdgcn_mfma_f32_16x16x32_bf16(af[mt], bfr[nt], acc[mt][nt], 0, 0, 0);
        }
    }

    if (BN_STATS) {
        if (tid < 128) { sred[tid][0] = 0.f; sred[tid][1] = 0.f; }
    }
    __syncthreads();

    #pragma unroll
    for (int nt = 0; nt < 4; nt++) {
        int col = tn + wn + nt * 16 + l16;
        float bv = (col < NN) ? bias[col] : 0.f;
        float s = 0.f, s2 = 0.f;
        #pragma unroll
        for (int mt = 0; mt < 4; mt++) {
            #pragma unroll
            for (int r = 0; r < 4; r++) {
                long row = tm + wm + mt * 16 + quad * 4 + r;
                float v = acc[mt][nt][r] + bv;
                if (ACT) v = fmaxf(v, 0.f);
                float sv = (col < NN) ? v : 0.f;
                if (col < store_cols) {
                    if (OUT_BF16) ((u16*)out)[row * out_stride + col] = f2bf(sv);
                    else          ((float*)out)[row * out_stride + col] = sv;
                }
                s += sv; s2 += sv * sv;
            }
        }
        if (BN_STATS) {
            atomicAdd(&sred[wn + nt * 16 + l16][0], s);
            atomicAdd(&sred[wn + nt * 16 + l16][1], s2);
        }
    }
    if (BN_STATS) {
        __syncthreads();
        if (tid < 128) {
            int col = tn + tid;
            if (col < NN) {
                atomicAdd(&stats[col], sred[tid][0]);
                atomicAdd(&stats[NN + col], sred[tid][1]);
            }
        }
    }
}

// ---------------- BN-apply + (relu) + residual (wave per node, u32 cols) ----------------
template<int RELU, int WRITE_HV>
__global__ __launch_bounds__(256) void resid_k(
    u32* __restrict__ hbf32, u32* __restrict__ hv32,
    const u32* __restrict__ z32, const float* __restrict__ stats,
    const float* __restrict__ scale, const float* __restrict__ bias, int l,
    const int* __restrict__ batch, const float* __restrict__ vn) {
    int tid = threadIdx.x;
    int wave = tid >> 6, lane = tid & 63;
    int n = blockIdx.x * 4 + wave;
    int g = WRITE_HV ? batch[n] : 0;
    #pragma unroll
    for (int p = 0; p < 3; p++) {
        int ii = lane + p * 64;
        if (ii >= 150) break;
        int c0 = 2 * ii;
        float m0 = stats[c0] * (1.f / (float)kN), m1 = stats[c0 + 1] * (1.f / (float)kN);
        float v0 = fmaxf(stats[kH + c0] * (1.f / (float)kN) - m0 * m0, 0.f);
        float v1 = fmaxf(stats[kH + c0 + 1] * (1.f / (float)kN) - m1 * m1, 0.f);
        float a0 = scale[l * kH + c0] * rsqrtf(v0 + 1e-5f);
        float a1 = scale[l * kH + c0 + 1] * rsqrtf(v1 + 1e-5f);
        float d0 = bias[l * kH + c0] - m0 * a0;
        float d1 = bias[l * kH + c0 + 1] - m1 * a1;
        u32 zz = z32[(long)n * HVS32 + ii];
        u32 hh = hbf32[(long)n * 150 + ii];
        float t0 = blo(zz) * a0 + d0;
        float t1 = bhi(zz) * a1 + d1;
        if (RELU) { t0 = fmaxf(t0, 0.f); t1 = fmaxf(t1, 0.f); }
        float h0 = blo(hh) + t0, h1 = bhi(hh) + t1;
        hbf32[(long)n * 150 + ii] = pack2(h0, h1);
        if (WRITE_HV) {
            float2 vv = *(const float2*)(vn + g * kH + c0);
            hv32[(long)n * HVS32 + ii] = pack2(h0 + vv.x, h1 + vv.y);
        }
    }
}

__global__ void vnupd_k(float* __restrict__ vn, const float* __restrict__ z) {
    int g = blockIdx.x, c = threadIdx.x;
    if (c < kH) vn[g * kH + c] += fmaxf(z[g * kH + c], 0.f);
}

// ---------------- h_rep cols [0,300): pooled mean of hbf (contiguous rows) ----------------
__global__ void pooled_k(const u16* __restrict__ hbf, const int* __restrict__ counts,
                         const int* __restrict__ starts, u16* __restrict__ hrep) {
    int g = blockIdx.x, c = threadIdx.x;
    if (c >= kH) return;
    int cnt = counts[g], st = starts[g];
    float acc = 0.f;
    for (int i = 0; i < cnt; i++) acc += bf2f(hbf[(long)(st + i) * kH + c]);
    acc /= (float)(cnt > 0 ? cnt : 1);
    hrep[(long)g * KP_DG + c] = f2bf(acc);
}

// ---------------- h_rep cols [300,1536): id_pool | morgan | maccs | zero-pad ----------------
__global__ void hrep_rest_k(const float* __restrict__ morgan, const float* __restrict__ maccs,
                            const int* __restrict__ counts, u16* __restrict__ hrep) {
    long idx = (long)blockIdx.x * 256 + threadIdx.x;
    if (idx >= (long)kG * (KP_DG - kH)) return;
    int g = (int)(idx / (KP_DG - kH));
    int j = (int)(idx % (KP_DG - kH));
    int col = kH + j;
    u16 v;
    if (j < kF) {
        int c = counts[g];
        int q = (j < c) ? ((c - 1 - j) / kF + 1) : 0;  // #k in [0,c) with k%32==j
        v = f2bf((float)q / (float)(c > 0 ? c : 1));
    } else if (j < kF + 1024) {
        v = f2bf(morgan[(long)g * 1024 + (j - kF)]);
    } else if (j < kF + 1024 + 167) {
        v = f2bf(maccs[(long)g * 167 + (j - kF - 1024)]);
    } else {
        v = 0;
    }
    hrep[(long)g * KP_DG + col] = v;
}

// ---------------- final: out[g] = zp[g,:600] . Wp2 + bp2 ----------------
__global__ void final_k(const u16* __restrict__ zp, const float* __restrict__ Wp2,
                        const float* __restrict__ bp2, float* __restrict__ out) {
    int wave = threadIdx.x >> 6, lane = threadIdx.x & 63;
    int g = blockIdx.x * 4 + wave;
    float acc = 0.f;
    for (int c = lane; c < kH2; c += 64) acc += bf2f(zp[(long)g * KP_H2 + c]) * Wp2[c];
    #pragma unroll
    for (int off = 32; off; off >>= 1) acc += __shfl_down(acc, off);
    if (lane == 0) out[g] = acc + bp2[0];
}

extern "C" void kernel_launch(void* const* d_in, const int* in_sizes, int n_in,
                              void* d_out, int out_size, void* d_ws, size_t ws_size,
                              hipStream_t stream) {
    const float* x      = (const float*)d_in[0];
    const float* morgan = (const float*)d_in[1];
    const float* maccs  = (const float*)d_in[2];
    const int*   ei     = (const int*)d_in[3];
    const int*   batch  = (const int*)d_in[4];
    const float* W_emb  = (const float*)d_in[5];
    const float* b_emb  = (const float*)d_in[6];
    const float* gin_W1 = (const float*)d_in[7];
    const float* gin_b1 = (const float*)d_in[8];
    const float* gin_W2 = (const float*)d_in[9];
    const float* gin_b2 = (const float*)d_in[10];
    const float* bn_scale = (const float*)d_in[11];
    const float* bn_bias  = (const float*)d_in[12];
    const float* eps    = (const float*)d_in[13];
    const float* vn0    = (const float*)d_in[14];
    const float* vn_W1  = (const float*)d_in[15];
    const float* vn_b1  = (const float*)d_in[16];
    const float* vn_W2  = (const float*)d_in[17];
    const float* vn_b2  = (const float*)d_in[18];
    const float* Wp1    = (const float*)d_in[19];
    const float* bp1    = (const float*)d_in[20];
    const float* Wp2    = (const float*)d_in[21];
    const float* bp2    = (const float*)d_in[22];
    float* out = (float*)d_out;

    char* ws = (char*)d_ws;
    size_t off = 0;
    auto alloc = [&](size_t bytes) -> char* {
        char* p = ws + off;
        off += (bytes + 255) & ~(size_t)255;
        return p;
    };
    u16*   hbf  = (u16*)alloc((size_t)kN * kH * 2);         // 39.3 MB bf16 h
    u16*   hvbf = (u16*)alloc((size_t)kN * HVS * 2);        // 41.9 MB bf16(h+vn[batch]), padded
    u16*   hv   = (u16*)alloc((size_t)kN * KP_H * 2);       // 41.9 MB (hv_in -> z2, in place)
    char*  S    = alloc((size_t)C_ROWS * KP_H2 * 2);        // 41.9 MB scratch region
    float* vn   = (float*)alloc((size_t)kG * kH * 4);       // 2.5 MB
    int* counts = (int*)alloc(kG * 4);
    int* starts = (int*)alloc(kG * 4);
    float* stats = (float*)alloc(2 * kH * 4);
    int* cnt_n  = (int*)alloc((size_t)kN * 4);
    int* start_n = (int*)alloc((size_t)(kN + 1) * 4);
    int* fill_n = (int*)alloc((size_t)kN * 4);
    int* bsum   = (int*)alloc((kN / 1024) * 4);
    int* perm   = (int*)alloc((size_t)kE * 4);
    u16* Wt_g1 = (u16*)alloc((size_t)kL * NP_H2 * KP_H * 2);
    u16* Wt_g2 = (u16*)alloc((size_t)kL * NP_H * KP_H2 * 2);
    u16* Wt_v1 = (u16*)alloc((size_t)(kL - 1) * NP_H2 * KP_H * 2);
    u16* Wt_v2 = (u16*)alloc((size_t)(kL - 1) * NP_H * KP_H2 * 2);
    u16* Wt_p1 = (u16*)alloc((size_t)NP_H2 * KP_DG * 2);
    if (off > ws_size) return;  // ~185 MB required

    // scratch-region overlays (disjoint lifetimes vs z1c chunk buffer):
    u16*   z1c   = (u16*)S;                                        // [32768, 640] bf16 (node chunks)
    u16*   vt_in = (u16*)S;                                        // [2048, 320] bf16
    u16*   z1v   = (u16*)(S + (size_t)kG * KP_H * 2);              // [2048, 640] bf16
    float* z2v   = (float*)(S + (size_t)kG * (KP_H + KP_H2) * 2);  // [2048, 300] f32
    u16*   hrep  = (u16*)S;                                        // [2048, 1536] bf16 (post-layers)
    u16*   zp    = (u16*)(S + (size_t)kG * KP_DG * 2);             // [2048, 640] bf16

    // weight transposes (f32 -> padded bf16)
    {
        long t1 = (long)kL * NP_H2 * KP_H;
        transpose_k<<<dim3((unsigned)((t1 + 255) / 256)), 256, 0, stream>>>(gin_W1, Wt_g1, kH, kH2, NP_H2, KP_H, t1);
        long t2 = (long)kL * NP_H * KP_H2;
        transpose_k<<<dim3((unsigned)((t2 + 255) / 256)), 256, 0, stream>>>(gin_W2, Wt_g2, kH2, kH, NP_H, KP_H2, t2);
        long t3 = (long)(kL - 1) * NP_H2 * KP_H;
        transpose_k<<<dim3((unsigned)((t3 + 255) / 256)), 256, 0, stream>>>(vn_W1, Wt_v1, kH, kH2, NP_H2, KP_H, t3);
        long t4 = (long)(kL - 1) * NP_H * KP_H2;
        transpose_k<<<dim3((unsigned)((t4 + 255) / 256)), 256, 0, stream>>>(vn_W2, Wt_v2, kH2, kH, NP_H, KP_H2, t4);
        long t5 = (long)NP_H2 * KP_DG;
        transpose_k<<<dim3((unsigned)((t5 + 255) / 256)), 256, 0, stream>>>(Wp1, Wt_p1, kDG, kH2, NP_H2, KP_DG, t5);
    }

    // graph ranges + node CSR
    hipMemsetAsync(counts, 0, kG * 4, stream);
    hipMemsetAsync(cnt_n, 0, (size_t)kN * 4, stream);
    hipMemsetAsync(fill_n, 0, (size_t)kN * 4, stream);
    hist_g_k<<<kN / 256, 256, 0, stream>>>(batch, counts);
    scan_g_k<<<1, 1024, 0, stream>>>(counts, starts);
    hist_n_k<<<kE / 256, 256, 0, stream>>>(ei, cnt_n);
    scanA_k<<<kN / 1024, 1024, 0, stream>>>(cnt_n, start_n, bsum);
    scanB_k<<<1, 64, 0, stream>>>(bsum);
    scanC_k<<<kN / 1024, 1024, 0, stream>>>(start_n, bsum);
    fill_n_k<<<kE / 256, 256, 0, stream>>>(ei, start_n, fill_n, perm);

    embed_k<<<kN / 4, 256, 0, stream>>>(x, W_emb, b_emb, (u32*)hbf, vn0, (u32*)hvbf);
    vninit_k<<<kG, 320, 0, stream>>>(vn0, vn);

    for (int l = 0; l < kL; l++) {
        gather_combine_k<<<kN / 4, 256, 0, stream>>>(
            (const u32*)hvbf, start_n, perm, eps, l, (u32*)hv, stats);
        if (l < kL - 1) {
            vt_fin_k<<<kG, 320, 0, stream>>>(hvbf, vn, counts, starts, vt_in);
            gemm_k<1, 1, 0><<<dim3(16, NP_H2 / 128), 256, 0, stream>>>(
                vt_in, Wt_v1 + (size_t)l * NP_H2 * KP_H, vn_b1 + l * kH2,
                z1v, nullptr, KP_H, kH2, KP_H2, KP_H2);
            gemm_k<0, 0, 0><<<dim3(16, NP_H / 128), 256, 0, stream>>>(
                z1v, Wt_v2 + (size_t)l * NP_H * KP_H2, vn_b2 + l * kH,
                z2v, nullptr, KP_H2, kH, kH, kH);
            vnupd_k<<<kG, 320, 0, stream>>>(vn, z2v);  // vn becomes vn_{l+1}
        }
        // node MLP in M-chunks; z2 (bf16) overwrites hv rows in place
        for (int c = 0; c < C_CHUNK; c++) {
            const u16* Ain = hv + (size_t)c * C_ROWS * KP_H;
            gemm_k<1, 1, 0><<<dim3(C_ROWS / 128, NP_H2 / 128), 256, 0, stream>>>(
                Ain, Wt_g1 + (size_t)l * NP_H2 * KP_H, gin_b1 + l * kH2,
                z1c, nullptr, KP_H, kH2, KP_H2, KP_H2);
            gemm_k<0, 1, 1><<<dim3(C_ROWS / 128, NP_H / 128), 256, 0, stream>>>(
                z1c, Wt_g2 + (size_t)l * NP_H * KP_H2, gin_b2 + l * kH,
                (void*)(hv + (size_t)c * C_ROWS * KP_H), stats, KP_H2, kH, KP_H, KP_H);
        }
        if (l < kL - 1)
            resid_k<1, 1><<<kN / 4, 256, 0, stream>>>(
                (u32*)hbf, (u32*)hvbf, (const u32*)hv, stats, bn_scale, bn_bias, l, batch, vn);
        else
            resid_k<0, 0><<<kN / 4, 256, 0, stream>>>(
                (u32*)hbf, (u32*)hvbf, (const u32*)hv, stats, bn_scale, bn_bias, l, batch, vn);
    }

    pooled_k<<<kG, 320, 0, stream>>>(hbf, counts, starts, hrep);
    {
        long tr = (long)kG * (KP_DG - kH);
        hrep_rest_k<<<dim3((unsigned)((tr + 255) / 256)), 256, 0, stream>>>(morgan, maccs, counts, hrep);
    }
    gemm_k<1, 1, 0><<<dim3(16, NP_H2 / 128), 256, 0, stream>>>(
        hrep, Wt_p1, bp1, zp, nullptr, KP_DG, kH2, KP_H2, KP_H2);
    final_k<<<kG / 4, 256, 0, stream>>>(zp, Wp2, bp2, out);
}

// Round 11
// 1524.627 us; speedup vs baseline: 2.1654x; 1.0073x over previous
//
#include <hip/hip_runtime.h>

typedef unsigned short u16;
typedef unsigned int u32;
typedef __attribute__((ext_vector_type(8))) short bf16x8_t;
typedef __attribute__((ext_vector_type(4))) float f32x4_t;

// problem constants
#define kN 65536
#define kE 262144
#define kG 2048
#define kH 300
#define kH2 600
#define kL 5
#define kF 32
#define kDG 1523
// padded dims
#define KP_H 320     // K pad of H (mult of 64)
#define KP_H2 640    // K pad of 2H
#define KP_DG 1536   // K pad of DG
#define NP_H2 640    // N pad of 2H (128-tiled)
#define NP_H 320     // N pad of H (64-tiled)
// M-chunking for node MLP
#define C_CHUNK 2
#define C_ROWS (kN / C_CHUNK)   // 32768
// hvbf row stride (u16 / u32)
#define HVS 320
#define HVS32 160

__device__ __forceinline__ float bf2f(u16 x) {
    union { u32 u; float f; } v; v.u = ((u32)x) << 16; return v.f;
}
__device__ __forceinline__ u16 f2bf(float f) {
    union { float f; u32 u; } v; v.f = f;
    u32 u = v.u;
    u32 r = (u + 0x7fffu + ((u >> 16) & 1u)) >> 16;  // RNE
    return (u16)r;
}
__device__ __forceinline__ float blo(u32 v) { return bf2f((u16)(v & 0xffffu)); }
__device__ __forceinline__ float bhi(u32 v) { return bf2f((u16)(v >> 16)); }
__device__ __forceinline__ u32 pack2(float lo, float hi) {
    return (u32)f2bf(lo) | ((u32)f2bf(hi) << 16);
}

// async 16B global -> LDS (wave-uniform lds base; lane writes base + lane*16)
__device__ __forceinline__ void gld16(const u16* g, u16* l) {
    __builtin_amdgcn_global_load_lds(
        (const __attribute__((address_space(1))) u32*)g,
        (__attribute__((address_space(3))) u32*)l, 16, 0, 0);
}

// ---------------- weight transpose: W[b][k][n] (f32) -> Wt[b][n][k] (bf16), zero-padded ----------------
__global__ void transpose_k(const float* __restrict__ W, u16* __restrict__ Wt,
                            int K, int NN, int NP, int KP, long total) {
    long idx = (long)blockIdx.x * 256 + threadIdx.x;
    if (idx >= total) return;
    int per = NP * KP;
    int b = (int)(idx / per);
    int r = (int)(idx % per);
    int n = r / KP;
    int k = r % KP;
    u16 v = 0;
    if (n < NN && k < K) v = f2bf(W[(long)b * K * NN + (long)k * NN + n]);
    Wt[idx] = v;
}

// ---------------- graph histogram + scan (G=2048) ----------------
__global__ void hist_g_k(const int* __restrict__ batch, int* __restrict__ counts) {
    int n = blockIdx.x * 256 + threadIdx.x;
    if (n < kN) atomicAdd(&counts[batch[n]], 1);
}

__global__ void scan_g_k(const int* __restrict__ counts, int* __restrict__ starts) {
    __shared__ int s[1024];
    int t = threadIdx.x;
    int c0 = counts[2 * t], c1 = counts[2 * t + 1];
    s[t] = c0 + c1;
    __syncthreads();
    for (int off = 1; off < 1024; off <<= 1) {
        int v = (t >= off) ? s[t - off] : 0;
        __syncthreads();
        s[t] += v;
        __syncthreads();
    }
    int excl = (t > 0) ? s[t - 1] : 0;
    starts[2 * t] = excl;
    starts[2 * t + 1] = excl + c0;
}

// ---------------- node CSR build (dst-sorted edges), 3-phase scan ----------------
__global__ void hist_n_k(const int* __restrict__ ei, int* __restrict__ cnt) {
    int e = blockIdx.x * 256 + threadIdx.x;
    if (e < kE) atomicAdd(&cnt[ei[kE + e]], 1);  // dst
}

__global__ void scanA_k(const int* __restrict__ cnt, int* __restrict__ start, int* __restrict__ bsum) {
    __shared__ int s[1024];
    int b = blockIdx.x, t = threadIdx.x;
    int v = cnt[b * 1024 + t];
    s[t] = v;
    __syncthreads();
    for (int off = 1; off < 1024; off <<= 1) {
        int u = (t >= off) ? s[t - off] : 0;
        __syncthreads();
        s[t] += u;
        __syncthreads();
    }
    start[b * 1024 + t] = s[t] - v;  // block-local exclusive
    if (t == 1023) bsum[b] = s[1023];
}

__global__ void scanB_k(int* __restrict__ bsum) {
    if (threadIdx.x == 0) {
        int s = 0;
        for (int i = 0; i < kN / 1024; i++) { s += bsum[i]; bsum[i] = s; }  // inclusive
    }
}

__global__ void scanC_k(int* __restrict__ start, const int* __restrict__ bsum) {
    int b = blockIdx.x, t = threadIdx.x;
    int add = (b > 0) ? bsum[b - 1] : 0;
    start[b * 1024 + t] += add;
    if (b == kN / 1024 - 1 && t == 1023) start[kN] = bsum[kN / 1024 - 1];
}

__global__ void fill_n_k(const int* __restrict__ ei, const int* __restrict__ start,
                         int* __restrict__ fill, int* __restrict__ perm) {
    int e = blockIdx.x * 256 + threadIdx.x;
    if (e >= kE) return;
    int s = ei[e], d = ei[kE + e];
    int pos = start[d] + atomicAdd(&fill[d], 1);
    perm[pos] = s;
}

// ---------------- node embedding (wave per node, u32 cols); W/b/vn0 staged in LDS ----------------
__global__ __launch_bounds__(256) void embed_k(
    const float* __restrict__ x, const float* __restrict__ W,
    const float* __restrict__ b, u32* __restrict__ hbf32,
    const float* __restrict__ vn0, u32* __restrict__ hv32) {
    __shared__ float sW[9 * kH];
    __shared__ float sB[kH];
    __shared__ float sV[kH];
    int tid = threadIdx.x;
    for (int i = tid; i < 9 * kH; i += 256) sW[i] = W[i];
    for (int i = tid; i < kH; i += 256) { sB[i] = b[i]; sV[i] = vn0[i]; }
    __syncthreads();
    int wave = tid >> 6, lane = tid & 63;
    int n = blockIdx.x * 4 + wave;
    float xv[9];
    #pragma unroll
    for (int d = 0; d < 9; d++) xv[d] = x[n * 9 + d];
    #pragma unroll
    for (int p = 0; p < 3; p++) {
        int ii = lane + p * 64;
        if (ii < 150) {
            int c0 = 2 * ii;
            float a0 = sB[c0], a1 = sB[c0 + 1];
            #pragma unroll
            for (int d = 0; d < 9; d++) {
                a0 += xv[d] * sW[d * kH + c0];
                a1 += xv[d] * sW[d * kH + c0 + 1];
            }
            hbf32[(long)n * 150 + ii] = pack2(a0, a1);
            hv32[(long)n * HVS32 + ii] = pack2(a0 + sV[c0], a1 + sV[c0 + 1]);
        } else if (ii < HVS32) {
            hv32[(long)n * HVS32 + ii] = 0u;
        }
    }
}

__global__ void vninit_k(const float* __restrict__ vn0, float* __restrict__ vn) {
    int g = blockIdx.x, c = threadIdx.x;
    if (c < kH) vn[g * kH + c] = vn0[c];
}

// ---------------- gather + combine: one WAVE per node, u32 (2-col) lanes, 4-wide unroll ----------------
__global__ __launch_bounds__(256) void gather_combine_k(
    const u32* __restrict__ hv32, const int* __restrict__ start_n,
    const int* __restrict__ perm, const float* __restrict__ eps, int l,
    u32* __restrict__ out32, float* __restrict__ stats) {
    int tid = threadIdx.x;
    int wave = tid >> 6, lane = tid & 63;
    int n = blockIdx.x * 4 + wave;
    int st = start_n[n], en = start_n[n + 1];
    int i0 = lane, i1 = lane + 64, i2 = lane + 128;
    bool p2 = (i2 < 150);
    float a0 = 0.f, b0 = 0.f, a1 = 0.f, b1 = 0.f, a2 = 0.f, b2 = 0.f;
    int e = st;
    for (; e + 4 <= en; e += 4) {
        const u32* rA = hv32 + (long)perm[e] * HVS32;
        const u32* rB = hv32 + (long)perm[e + 1] * HVS32;
        const u32* rC = hv32 + (long)perm[e + 2] * HVS32;
        const u32* rD = hv32 + (long)perm[e + 3] * HVS32;
        u32 vA0 = rA[i0], vA1 = rA[i1], vA2 = p2 ? rA[i2] : 0u;
        u32 vB0 = rB[i0], vB1 = rB[i1], vB2 = p2 ? rB[i2] : 0u;
        u32 vC0 = rC[i0], vC1 = rC[i1], vC2 = p2 ? rC[i2] : 0u;
        u32 vD0 = rD[i0], vD1 = rD[i1], vD2 = p2 ? rD[i2] : 0u;
        a0 += (blo(vA0) + blo(vB0)) + (blo(vC0) + blo(vD0));
        b0 += (bhi(vA0) + bhi(vB0)) + (bhi(vC0) + bhi(vD0));
        a1 += (blo(vA1) + blo(vB1)) + (blo(vC1) + blo(vD1));
        b1 += (bhi(vA1) + bhi(vB1)) + (bhi(vC1) + bhi(vD1));
        a2 += (blo(vA2) + blo(vB2)) + (blo(vC2) + blo(vD2));
        b2 += (bhi(vA2) + bhi(vB2)) + (bhi(vC2) + bhi(vD2));
    }
    for (; e + 2 <= en; e += 2) {
        const u32* rA = hv32 + (long)perm[e] * HVS32;
        const u32* rB = hv32 + (long)perm[e + 1] * HVS32;
        u32 vA0 = rA[i0], vA1 = rA[i1], vA2 = p2 ? rA[i2] : 0u;
        u32 vB0 = rB[i0], vB1 = rB[i1], vB2 = p2 ? rB[i2] : 0u;
        a0 += blo(vA0) + blo(vB0); b0 += bhi(vA0) + bhi(vB0);
        a1 += blo(vA1) + blo(vB1); b1 += bhi(vA1) + bhi(vB1);
        a2 += blo(vA2) + blo(vB2); b2 += bhi(vA2) + bhi(vB2);
    }
    if (e < en) {
        const u32* rA = hv32 + (long)perm[e] * HVS32;
        u32 vA0 = rA[i0], vA1 = rA[i1], vA2 = p2 ? rA[i2] : 0u;
        a0 += blo(vA0); b0 += bhi(vA0);
        a1 += blo(vA1); b1 += bhi(vA1);
        a2 += blo(vA2); b2 += bhi(vA2);
    }
    const u32* self = hv32 + (long)n * HVS32;
    float ep = 1.f + eps[l];
    u32 s0 = self[i0], s1 = self[i1];
    u32* o = out32 + (long)n * HVS32;
    o[i0] = pack2(ep * blo(s0) + a0, ep * bhi(s0) + b0);
    o[i1] = pack2(ep * blo(s1) + a1, ep * bhi(s1) + b1);
    if (p2) {
        u32 s2 = self[i2];
        o[i2] = pack2(ep * blo(s2) + a2, ep * bhi(s2) + b2);
    } else if (i2 < HVS32) {
        o[i2] = 0u;  // K-pad cols 300..319
    }
    int gz = blockIdx.x * 256 + tid;
    if (gz < 2 * kH) stats[gz] = 0.f;
}

// ---------------- vt_in[g] = bf16(sum_{rows of g} hvbf + vn[g]) (contiguous rows) ----------------
__global__ void vt_fin_k(const u16* __restrict__ hvbf, const float* __restrict__ vn,
                         const int* __restrict__ counts, const int* __restrict__ starts,
                         u16* __restrict__ vt_in) {
    int g = blockIdx.x, c = threadIdx.x;  // 320
    if (c >= kH) { vt_in[(long)g * KP_H + c] = 0; return; }
    int cnt = counts[g], st = starts[g];
    float acc = vn[g * kH + c];
    for (int i = 0; i < cnt; i++) acc += bf2f(hvbf[(long)(st + i) * HVS + c]);
    vt_in[(long)g * KP_H + c] = f2bf(acc);
}

// ---------------- GEMM: 128x128 tile, BK=64, global_load_lds + XOR-swizzled LDS ----------------
template<int ACT, int OUT_BF16, int BN_STATS>
__global__ __launch_bounds__(256) void gemm_k(
    const u16* __restrict__ A, const u16* __restrict__ Wt,
    const float* __restrict__ bias, void* __restrict__ out,
    float* __restrict__ stats,
    int KP, int NN, int out_stride, int store_cols) {
    __shared__ __align__(16) u16 lA[128 * 64];
    __shared__ __align__(16) u16 lB[128 * 64];
    __shared__ float sred[128][2];

    const int tid = threadIdx.x;
    const int lane = tid & 63;
    const int wave = tid >> 6;
    const int l16 = lane & 15;
    const int quad = lane >> 4;
    const int wm = (wave & 1) * 64;
    const int wn = (wave >> 1) * 64;
    const long tm = (long)blockIdx.x * 128;
    const int tn = blockIdx.y * 128;

    const int srow = lane >> 3;
    const int sch = (lane & 7) ^ srow;

    f32x4_t acc[4][4];
    #pragma unroll
    for (int i = 0; i < 4; i++)
        #pragma unroll
        for (int j = 0; j < 4; j++) acc[i][j] = (f32x4_t){0.f, 0.f, 0.f, 0.f};

    for (int k0 = 0; k0 < KP; k0 += 64) {
        __syncthreads();
        #pragma unroll
        for (int j = 0; j < 4; j++) {
            int rb = wave * 32 + j * 8;
            int r = rb + srow;
            gld16(A + (tm + r) * KP + k0 + sch * 8, &lA[rb * 64]);
            gld16(Wt + (long)(tn + r) * KP + k0 + sch * 8, &lB[rb * 64]);
        }
        __syncthreads();
        #pragma unroll
        for (int ks = 0; ks < 2; ks++) {
            bf16x8_t af[4], bfr[4];
            #pragma unroll
            for (int mt = 0; mt < 4; mt++) {
                int row = wm + mt * 16 + l16;
                int phys = (ks * 4 + quad) ^ (l16 & 7);
                af[mt] = *(const bf16x8_t*)&lA[row * 64 + phys * 8];
            }
            #pragma unroll
            for (int nt = 0; nt < 4; nt++) {
                int row = wn + nt * 16 + l16;
                int phys = (ks * 4 + quad) ^ (l16 & 7);
                bfr[nt] = *(const bf16x8_t*)&lB[row * 64 + phys * 8];
            }
            #pragma unroll
            for (int mt = 0; mt < 4; mt++)
                #pragma unroll
                for (int nt = 0; nt < 4; nt++)
                    acc[mt][nt] = __builtin_amdgcn_mfma_f32_16x16x32_bf16(af[mt], bfr[nt], acc[mt][nt], 0, 0, 0);
        }
    }

    if (BN_STATS) {
        if (tid < 128) { sred[tid][0] = 0.f; sred[tid][1] = 0.f; }
    }
    __syncthreads();

    #pragma unroll
    for (int nt = 0; nt < 4; nt++) {
        int col = tn + wn + nt * 16 + l16;
        float bv = (col < NN) ? bias[col] : 0.f;
        float s = 0.f, s2 = 0.f;
        #pragma unroll
        for (int mt = 0; mt < 4; mt++) {
            #pragma unroll
            for (int r = 0; r < 4; r++) {
                long row = tm + wm + mt * 16 + quad * 4 + r;
                float v = acc[mt][nt][r] + bv;
                if (ACT) v = fmaxf(v, 0.f);
                float sv = (col < NN) ? v : 0.f;
                if (col < store_cols) {
                    if (OUT_BF16) ((u16*)out)[row * out_stride + col] = f2bf(sv);
                    else          ((float*)out)[row * out_stride + col] = sv;
                }
                s += sv; s2 += sv * sv;
            }
        }
        if (BN_STATS) {
            atomicAdd(&sred[wn + nt * 16 + l16][0], s);
            atomicAdd(&sred[wn + nt * 16 + l16][1], s2);
        }
    }
    if (BN_STATS) {
        __syncthreads();
        if (tid < 128) {
            int col = tn + tid;
            if (col < NN) {
                atomicAdd(&stats[col], sred[tid][0]);
                atomicAdd(&stats[NN + col], sred[tid][1]);
            }
        }
    }
}

// ---------------- GEMM64: 128x64 tile, BK=64 (for N=300/320 outputs — less pad waste) ----------------
template<int ACT, int OUT_BF16, int BN_STATS>
__global__ __launch_bounds__(256) void gemm64_k(
    const u16* __restrict__ A, const u16* __restrict__ Wt,
    const float* __restrict__ bias, void* __restrict__ out,
    float* __restrict__ stats,
    int KP, int NN, int out_stride, int store_cols) {
    __shared__ __align__(16) u16 lA[128 * 64];
    __shared__ __align__(16) u16 lB[64 * 64];
    __shared__ float sred[64][2];

    const int tid = threadIdx.x;
    const int lane = tid & 63;
    const int wave = tid >> 6;
    const int l16 = lane & 15;
    const int quad = lane >> 4;
    const int wm = (wave & 1) * 64;
    const int wn = (wave >> 1) * 32;
    const long tm = (long)blockIdx.x * 128;
    const int tn = blockIdx.y * 64;

    const int srow = lane >> 3;
    const int sch = (lane & 7) ^ srow;

    f32x4_t acc[4][2];
    #pragma unroll
    for (int i = 0; i < 4; i++)
        #pragma unroll
        for (int j = 0; j < 2; j++) acc[i][j] = (f32x4_t){0.f, 0.f, 0.f, 0.f};

    for (int k0 = 0; k0 < KP; k0 += 64) {
        __syncthreads();
        #pragma unroll
        for (int j = 0; j < 4; j++) {
            int rb = wave * 32 + j * 8;
            gld16(A + (tm + rb + srow) * KP + k0 + sch * 8, &lA[rb * 64]);
        }
        #pragma unroll
        for (int j = 0; j < 2; j++) {
            int rb = wave * 16 + j * 8;
            gld16(Wt + (long)(tn + rb + srow) * KP + k0 + sch * 8, &lB[rb * 64]);
        }
        __syncthreads();
        #pragma unroll
        for (int ks = 0; ks < 2; ks++) {
            bf16x8_t af[4], bfr[2];
            #pragma unroll
            for (int mt = 0; mt < 4; mt++) {
                int row = wm + mt * 16 + l16;
                int phys = (ks * 4 + quad) ^ (l16 & 7);
                af[mt] = *(const bf16x8_t*)&lA[row * 64 + phys * 8];
            }
            #pragma unroll
            for (int nt = 0; nt < 2; nt++) {
                int row = wn + nt * 16 + l16;
                int phys = (ks * 4 + quad) ^ (l16 & 7);
                bfr[nt] = *(const bf16x8_t*)&lB[row * 64 + phys * 8];
            }
            #pragma unroll
            for (int mt = 0; mt < 4; mt++)
                #pragma unroll
                for (int nt = 0; nt < 2; nt++)
                    acc[mt][nt] = __builtin_amdgcn_mfma_f32_16x16x32_bf16(af[mt], bfr[nt], acc[mt][nt], 0, 0, 0);
        }
    }

    if (BN_STATS) {
        if (tid < 64) { sred[tid][0] = 0.f; sred[tid][1] = 0.f; }
    }
    __syncthreads();

    #pragma unroll
    for (int nt = 0; nt < 2; nt++) {
        int col = tn + wn + nt * 16 + l16;
        float bv = (col < NN) ? bias[col] : 0.f;
        float s = 0.f, s2 = 0.f;
        #pragma unroll
        for (int mt = 0; mt < 4; mt++) {
            #pragma unroll
            for (int r = 0; r < 4; r++) {
                long row = tm + wm + mt * 16 + quad * 4 + r;
                float v = acc[mt][nt][r] + bv;
                if (ACT) v = fmaxf(v, 0.f);
                float sv = (col < NN) ? v : 0.f;
                if (col < store_cols) {
                    if (OUT_BF16) ((u16*)out)[row * out_stride + col] = f2bf(sv);
                    else          ((float*)out)[row * out_stride + col] = sv;
                }
                s += sv; s2 += sv * sv;
            }
        }
        if (BN_STATS) {
            atomicAdd(&sred[wn + nt * 16 + l16][0], s);
            atomicAdd(&sred[wn + nt * 16 + l16][1], s2);
        }
    }
    if (BN_STATS) {
        __syncthreads();
        if (tid < 64) {
            int col = tn + tid;
            if (col < NN) {
                atomicAdd(&stats[col], sred[tid][0]);
                atomicAdd(&stats[NN + col], sred[tid][1]);
            }
        }
    }
}

// ---------------- BN-apply + (relu) + residual (wave per node, u32 cols) ----------------
template<int RELU, int WRITE_HV>
__global__ __launch_bounds__(256) void resid_k(
    u32* __restrict__ hbf32, u32* __restrict__ hv32,
    const u32* __restrict__ z32, const float* __restrict__ stats,
    const float* __restrict__ scale, const float* __restrict__ bias, int l,
    const int* __restrict__ batch, const float* __restrict__ vn) {
    int tid = threadIdx.x;
    int wave = tid >> 6, lane = tid & 63;
    int n = blockIdx.x * 4 + wave;
    int g = WRITE_HV ? batch[n] : 0;
    #pragma unroll
    for (int p = 0; p < 3; p++) {
        int ii = lane + p * 64;
        if (ii >= 150) break;
        int c0 = 2 * ii;
        float m0 = stats[c0] * (1.f / (float)kN), m1 = stats[c0 + 1] * (1.f / (float)kN);
        float v0 = fmaxf(stats[kH + c0] * (1.f / (float)kN) - m0 * m0, 0.f);
        float v1 = fmaxf(stats[kH + c0 + 1] * (1.f / (float)kN) - m1 * m1, 0.f);
        float a0 = scale[l * kH + c0] * rsqrtf(v0 + 1e-5f);
        float a1 = scale[l * kH + c0 + 1] * rsqrtf(v1 + 1e-5f);
        float d0 = bias[l * kH + c0] - m0 * a0;
        float d1 = bias[l * kH + c0 + 1] - m1 * a1;
        u32 zz = z32[(long)n * HVS32 + ii];
        u32 hh = hbf32[(long)n * 150 + ii];
        float t0 = blo(zz) * a0 + d0;
        float t1 = bhi(zz) * a1 + d1;
        if (RELU) { t0 = fmaxf(t0, 0.f); t1 = fmaxf(t1, 0.f); }
        float h0 = blo(hh) + t0, h1 = bhi(hh) + t1;
        hbf32[(long)n * 150 + ii] = pack2(h0, h1);
        if (WRITE_HV) {
            float2 vv = *(const float2*)(vn + g * kH + c0);
            hv32[(long)n * HVS32 + ii] = pack2(h0 + vv.x, h1 + vv.y);
        }
    }
}

__global__ void vnupd_k(float* __restrict__ vn, const float* __restrict__ z) {
    int g = blockIdx.x, c = threadIdx.x;
    if (c < kH) vn[g * kH + c] += fmaxf(z[g * kH + c], 0.f);
}

// ---------------- h_rep cols [0,300): pooled mean of hbf (contiguous rows) ----------------
__global__ void pooled_k(const u16* __restrict__ hbf, const int* __restrict__ counts,
                         const int* __restrict__ starts, u16* __restrict__ hrep) {
    int g = blockIdx.x, c = threadIdx.x;
    if (c >= kH) return;
    int cnt = counts[g], st = starts[g];
    float acc = 0.f;
    for (int i = 0; i < cnt; i++) acc += bf2f(hbf[(long)(st + i) * kH + c]);
    acc /= (float)(cnt > 0 ? cnt : 1);
    hrep[(long)g * KP_DG + c] = f2bf(acc);
}

// ---------------- h_rep cols [300,1536): id_pool | morgan | maccs | zero-pad ----------------
__global__ void hrep_rest_k(const float* __restrict__ morgan, const float* __restrict__ maccs,
                            const int* __restrict__ counts, u16* __restrict__ hrep) {
    long idx = (long)blockIdx.x * 256 + threadIdx.x;
    if (idx >= (long)kG * (KP_DG - kH)) return;
    int g = (int)(idx / (KP_DG - kH));
    int j = (int)(idx % (KP_DG - kH));
    int col = kH + j;
    u16 v;
    if (j < kF) {
        int c = counts[g];
        int q = (j < c) ? ((c - 1 - j) / kF + 1) : 0;  // #k in [0,c) with k%32==j
        v = f2bf((float)q / (float)(c > 0 ? c : 1));
    } else if (j < kF + 1024) {
        v = f2bf(morgan[(long)g * 1024 + (j - kF)]);
    } else if (j < kF + 1024 + 167) {
        v = f2bf(maccs[(long)g * 167 + (j - kF - 1024)]);
    } else {
        v = 0;
    }
    hrep[(long)g * KP_DG + col] = v;
}

// ---------------- final: out[g] = zp[g,:600] . Wp2 + bp2 ----------------
__global__ void final_k(const u16* __restrict__ zp, const float* __restrict__ Wp2,
                        const float* __restrict__ bp2, float* __restrict__ out) {
    int wave = threadIdx.x >> 6, lane = threadIdx.x & 63;
    int g = blockIdx.x * 4 + wave;
    float acc = 0.f;
    for (int c = lane; c < kH2; c += 64) acc += bf2f(zp[(long)g * KP_H2 + c]) * Wp2[c];
    #pragma unroll
    for (int off = 32; off; off >>= 1) acc += __shfl_down(acc, off);
    if (lane == 0) out[g] = acc + bp2[0];
}

extern "C" void kernel_launch(void* const* d_in, const int* in_sizes, int n_in,
                              void* d_out, int out_size, void* d_ws, size_t ws_size,
                              hipStream_t stream) {
    const float* x      = (const float*)d_in[0];
    const float* morgan = (const float*)d_in[1];
    const float* maccs  = (const float*)d_in[2];
    const int*   ei     = (const int*)d_in[3];
    const int*   batch  = (const int*)d_in[4];
    const float* W_emb  = (const float*)d_in[5];
    const float* b_emb  = (const float*)d_in[6];
    const float* gin_W1 = (const float*)d_in[7];
    const float* gin_b1 = (const float*)d_in[8];
    const float* gin_W2 = (const float*)d_in[9];
    const float* gin_b2 = (const float*)d_in[10];
    const float* bn_scale = (const float*)d_in[11];
    const float* bn_bias  = (const float*)d_in[12];
    const float* eps    = (const float*)d_in[13];
    const float* vn0    = (const float*)d_in[14];
    const float* vn_W1  = (const float*)d_in[15];
    const float* vn_b1  = (const float*)d_in[16];
    const float* vn_W2  = (const float*)d_in[17];
    const float* vn_b2  = (const float*)d_in[18];
    const float* Wp1    = (const float*)d_in[19];
    const float* bp1    = (const float*)d_in[20];
    const float* Wp2    = (const float*)d_in[21];
    const float* bp2    = (const float*)d_in[22];
    float* out = (float*)d_out;

    char* ws = (char*)d_ws;
    size_t off = 0;
    auto alloc = [&](size_t bytes) -> char* {
        char* p = ws + off;
        off += (bytes + 255) & ~(size_t)255;
        return p;
    };
    u16*   hbf  = (u16*)alloc((size_t)kN * kH * 2);         // 39.3 MB bf16 h
    u16*   hvbf = (u16*)alloc((size_t)kN * HVS * 2);        // 41.9 MB bf16(h+vn[batch]), padded
    u16*   hv   = (u16*)alloc((size_t)kN * KP_H * 2);       // 41.9 MB (hv_in -> z2, in place)
    char*  S    = alloc((size_t)C_ROWS * KP_H2 * 2);        // 41.9 MB scratch region
    float* vn   = (float*)alloc((size_t)kG * kH * 4);       // 2.5 MB
    int* counts = (int*)alloc(kG * 4);
    int* starts = (int*)alloc(kG * 4);
    float* stats = (float*)alloc(2 * kH * 4);
    int* cnt_n  = (int*)alloc((size_t)kN * 4);
    int* start_n = (int*)alloc((size_t)(kN + 1) * 4);
    int* fill_n = (int*)alloc((size_t)kN * 4);
    int* bsum   = (int*)alloc((kN / 1024) * 4);
    int* perm   = (int*)alloc((size_t)kE * 4);
    u16* Wt_g1 = (u16*)alloc((size_t)kL * NP_H2 * KP_H * 2);
    u16* Wt_g2 = (u16*)alloc((size_t)kL * NP_H * KP_H2 * 2);
    u16* Wt_v1 = (u16*)alloc((size_t)(kL - 1) * NP_H2 * KP_H * 2);
    u16* Wt_v2 = (u16*)alloc((size_t)(kL - 1) * NP_H * KP_H2 * 2);
    u16* Wt_p1 = (u16*)alloc((size_t)NP_H2 * KP_DG * 2);
    if (off > ws_size) return;  // ~184 MB required

    // scratch-region overlays (disjoint lifetimes vs z1c chunk buffer):
    u16*   z1c   = (u16*)S;                                        // [32768, 640] bf16 (node chunks)
    u16*   vt_in = (u16*)S;                                        // [2048, 320] bf16
    u16*   z1v   = (u16*)(S + (size_t)kG * KP_H * 2);              // [2048, 640] bf16
    float* z2v   = (float*)(S + (size_t)kG * (KP_H + KP_H2) * 2);  // [2048, 300] f32
    u16*   hrep  = (u16*)S;                                        // [2048, 1536] bf16 (post-layers)
    u16*   zp    = (u16*)(S + (size_t)kG * KP_DG * 2);             // [2048, 640] bf16

    // weight transposes (f32 -> padded bf16)
    {
        long t1 = (long)kL * NP_H2 * KP_H;
        transpose_k<<<dim3((unsigned)((t1 + 255) / 256)), 256, 0, stream>>>(gin_W1, Wt_g1, kH, kH2, NP_H2, KP_H, t1);
        long t2 = (long)kL * NP_H * KP_H2;
        transpose_k<<<dim3((unsigned)((t2 + 255) / 256)), 256, 0, stream>>>(gin_W2, Wt_g2, kH2, kH, NP_H, KP_H2, t2);
        long t3 = (long)(kL - 1) * NP_H2 * KP_H;
        transpose_k<<<dim3((unsigned)((t3 + 255) / 256)), 256, 0, stream>>>(vn_W1, Wt_v1, kH, kH2, NP_H2, KP_H, t3);
        long t4 = (long)(kL - 1) * NP_H * KP_H2;
        transpose_k<<<dim3((unsigned)((t4 + 255) / 256)), 256, 0, stream>>>(vn_W2, Wt_v2, kH2, kH, NP_H, KP_H2, t4);
        long t5 = (long)NP_H2 * KP_DG;
        transpose_k<<<dim3((unsigned)((t5 + 255) / 256)), 256, 0, stream>>>(Wp1, Wt_p1, kDG, kH2, NP_H2, KP_DG, t5);
    }

    // graph ranges + node CSR
    hipMemsetAsync(counts, 0, kG * 4, stream);
    hipMemsetAsync(cnt_n, 0, (size_t)kN * 4, stream);
    hipMemsetAsync(fill_n, 0, (size_t)kN * 4, stream);
    hist_g_k<<<kN / 256, 256, 0, stream>>>(batch, counts);
    scan_g_k<<<1, 1024, 0, stream>>>(counts, starts);
    hist_n_k<<<kE / 256, 256, 0, stream>>>(ei, cnt_n);
    scanA_k<<<kN / 1024, 1024, 0, stream>>>(cnt_n, start_n, bsum);
    scanB_k<<<1, 64, 0, stream>>>(bsum);
    scanC_k<<<kN / 1024, 1024, 0, stream>>>(start_n, bsum);
    fill_n_k<<<kE / 256, 256, 0, stream>>>(ei, start_n, fill_n, perm);

    embed_k<<<kN / 4, 256, 0, stream>>>(x, W_emb, b_emb, (u32*)hbf, vn0, (u32*)hvbf);
    vninit_k<<<kG, 320, 0, stream>>>(vn0, vn);

    for (int l = 0; l < kL; l++) {
        gather_combine_k<<<kN / 4, 256, 0, stream>>>(
            (const u32*)hvbf, start_n, perm, eps, l, (u32*)hv, stats);
        if (l < kL - 1) {
            vt_fin_k<<<kG, 320, 0, stream>>>(hvbf, vn, counts, starts, vt_in);
            gemm_k<1, 1, 0><<<dim3(16, NP_H2 / 128), 256, 0, stream>>>(
                vt_in, Wt_v1 + (size_t)l * NP_H2 * KP_H, vn_b1 + l * kH2,
                z1v, nullptr, KP_H, kH2, KP_H2, KP_H2);
            gemm64_k<0, 0, 0><<<dim3(16, NP_H / 64), 256, 0, stream>>>(
                z1v, Wt_v2 + (size_t)l * NP_H * KP_H2, vn_b2 + l * kH,
                z2v, nullptr, KP_H2, kH, kH, kH);
            vnupd_k<<<kG, 320, 0, stream>>>(vn, z2v);  // vn becomes vn_{l+1}
        }
        // node MLP in M-chunks; z2 (bf16) overwrites hv rows in place
        for (int c = 0; c < C_CHUNK; c++) {
            const u16* Ain = hv + (size_t)c * C_ROWS * KP_H;
            gemm_k<1, 1, 0><<<dim3(C_ROWS / 128, NP_H2 / 128), 256, 0, stream>>>(
                Ain, Wt_g1 + (size_t)l * NP_H2 * KP_H, gin_b1 + l * kH2,
                z1c, nullptr, KP_H, kH2, KP_H2, KP_H2);
            gemm64_k<0, 1, 1><<<dim3(C_ROWS / 128, NP_H / 64), 256, 0, stream>>>(
                z1c, Wt_g2 + (size_t)l * NP_H * KP_H2, gin_b2 + l * kH,
                (void*)(hv + (size_t)c * C_ROWS * KP_H), stats, KP_H2, kH, KP_H, KP_H);
        }
        if (l < kL - 1)
            resid_k<1, 1><<<kN / 4, 256, 0, stream>>>(
                (u32*)hbf, (u32*)hvbf, (const u32*)hv, stats, bn_scale, bn_bias, l, batch, vn);
        else
            resid_k<0, 0><<<kN / 4, 256, 0, stream>>>(
                (u32*)hbf, (u32*)hvbf, (const u32*)hv, stats, bn_scale, bn_bias, l, batch, vn);
    }

    pooled_k<<<kG, 320, 0, stream>>>(hbf, counts, starts, hrep);
    {
        long tr = (long)kG * (KP_DG - kH);
        hrep_rest_k<<<dim3((unsigned)((tr + 255) / 256)), 256, 0, stream>>>(morgan, maccs, counts, hrep);
    }
    gemm_k<1, 1, 0><<<dim3(16, NP_H2 / 128), 256, 0, stream>>>(
        hrep, Wt_p1, bp1, zp, nullptr, KP_DG, kH2, KP_H2, KP_H2);
    final_k<<<kG / 4, 256, 0, stream>>>(zp, Wp2, bp2, out);
}

// Round 13
// 1499.015 us; speedup vs baseline: 2.2024x; 1.0171x over previous
//
#include <hip/hip_runtime.h>

typedef unsigned short u16;
typedef unsigned int u32;
typedef __attribute__((ext_vector_type(8))) short bf16x8_t;
typedef __attribute__((ext_vector_type(4))) float f32x4_t;

// problem constants
#define kN 65536
#define kE 262144
#define kG 2048
#define kH 300
#define kH2 600
#define kL 5
#define kF 32
#define kDG 1523
// padded dims
#define KP_H 320     // K pad of H
#define KP_H2 640    // K pad of 2H
#define KP_DG 1536   // K pad of DG
#define NP_H2 640    // N pad of 2H (128-tiled)
#define NP_H 320     // N pad of H (64-tiled)
// hvbf row stride (u16 / u32)
#define HVS 320
#define HVS32 160

__device__ __forceinline__ float bf2f(u16 x) {
    union { u32 u; float f; } v; v.u = ((u32)x) << 16; return v.f;
}
__device__ __forceinline__ u16 f2bf(float f) {
    union { float f; u32 u; } v; v.f = f;
    u32 u = v.u;
    u32 r = (u + 0x7fffu + ((u >> 16) & 1u)) >> 16;  // RNE
    return (u16)r;
}
__device__ __forceinline__ float blo(u32 v) { return bf2f((u16)(v & 0xffffu)); }
__device__ __forceinline__ float bhi(u32 v) { return bf2f((u16)(v >> 16)); }
__device__ __forceinline__ u32 pack2(float lo, float hi) {
    return (u32)f2bf(lo) | ((u32)f2bf(hi) << 16);
}

// async 16B global -> LDS
__device__ __forceinline__ void gld16(const u16* g, u16* l) {
    __builtin_amdgcn_global_load_lds(
        (const __attribute__((address_space(1))) u32*)g,
        (__attribute__((address_space(3))) u32*)l, 16, 0, 0);
}

// ---------------- weight transpose: W[b][k][n] (f32) -> Wt[b][n][k] (bf16), zero-padded ----------------
__global__ void transpose_k(const float* __restrict__ W, u16* __restrict__ Wt,
                            int K, int NN, int NP, int KP, long total) {
    long idx = (long)blockIdx.x * 256 + threadIdx.x;
    if (idx >= total) return;
    int per = NP * KP;
    int b = (int)(idx / per);
    int r = (int)(idx % per);
    int n = r / KP;
    int k = r % KP;
    u16 v = 0;
    if (n < NN && k < K) v = f2bf(W[(long)b * K * NN + (long)k * NN + n]);
    Wt[idx] = v;
}

// ---------------- graph histogram + scan ----------------
__global__ void hist_g_k(const int* __restrict__ batch, int* __restrict__ counts) {
    int n = blockIdx.x * 256 + threadIdx.x;
    if (n < kN) atomicAdd(&counts[batch[n]], 1);
}

__global__ void scan_g_k(const int* __restrict__ counts, int* __restrict__ starts) {
    __shared__ int s[1024];
    int t = threadIdx.x;
    int c0 = counts[2 * t], c1 = counts[2 * t + 1];
    s[t] = c0 + c1;
    __syncthreads();
    for (int off = 1; off < 1024; off <<= 1) {
        int v = (t >= off) ? s[t - off] : 0;
        __syncthreads();
        s[t] += v;
        __syncthreads();
    }
    int excl = (t > 0) ? s[t - 1] : 0;
    starts[2 * t] = excl;
    starts[2 * t + 1] = excl + c0;
}

// ---------------- node CSR build ----------------
__global__ void hist_n_k(const int* __restrict__ ei, int* __restrict__ cnt) {
    int e = blockIdx.x * 256 + threadIdx.x;
    if (e < kE) atomicAdd(&cnt[ei[kE + e]], 1);
}

__global__ void scanA_k(const int* __restrict__ cnt, int* __restrict__ start, int* __restrict__ bsum) {
    __shared__ int s[1024];
    int b = blockIdx.x, t = threadIdx.x;
    int v = cnt[b * 1024 + t];
    s[t] = v;
    __syncthreads();
    for (int off = 1; off < 1024; off <<= 1) {
        int u = (t >= off) ? s[t - off] : 0;
        __syncthreads();
        s[t] += u;
        __syncthreads();
    }
    start[b * 1024 + t] = s[t] - v;
    if (t == 1023) bsum[b] = s[1023];
}

__global__ void scanB_k(int* __restrict__ bsum) {
    if (threadIdx.x == 0) {
        int s = 0;
        for (int i = 0; i < kN / 1024; i++) { s += bsum[i]; bsum[i] = s; }
    }
}

__global__ void scanC_k(int* __restrict__ start, const int* __restrict__ bsum) {
    int b = blockIdx.x, t = threadIdx.x;
    int add = (b > 0) ? bsum[b - 1] : 0;
    start[b * 1024 + t] += add;
    if (b == kN / 1024 - 1 && t == 1023) start[kN] = bsum[kN / 1024 - 1];
}

__global__ void fill_n_k(const int* __restrict__ ei, const int* __restrict__ start,
                         int* __restrict__ fill, int* __restrict__ perm) {
    int e = blockIdx.x * 256 + threadIdx.x;
    if (e >= kE) return;
    int s = ei[e], d = ei[kE + e];
    int pos = start[d] + atomicAdd(&fill[d], 1);
    perm[pos] = s;
}

// ---------------- node embedding: hvbf = bf16(x@W+b + vn0) (only buffer) ----------------
__global__ __launch_bounds__(256) void embed_k(
    const float* __restrict__ x, const float* __restrict__ W,
    const float* __restrict__ b, const float* __restrict__ vn0,
    u32* __restrict__ hv32) {
    __shared__ float sW[9 * kH];
    __shared__ float sBV[kH];  // b + vn0 combined
    int tid = threadIdx.x;
    for (int i = tid; i < 9 * kH; i += 256) sW[i] = W[i];
    for (int i = tid; i < kH; i += 256) sBV[i] = b[i] + vn0[i];
    __syncthreads();
    int wave = tid >> 6, lane = tid & 63;
    int n = blockIdx.x * 4 + wave;
    float xv[9];
    #pragma unroll
    for (int d = 0; d < 9; d++) xv[d] = x[n * 9 + d];
    #pragma unroll
    for (int p = 0; p < 3; p++) {
        int ii = lane + p * 64;
        if (ii < 150) {
            int c0 = 2 * ii;
            float a0 = sBV[c0], a1 = sBV[c0 + 1];
            #pragma unroll
            for (int d = 0; d < 9; d++) {
                a0 += xv[d] * sW[d * kH + c0];
                a1 += xv[d] * sW[d * kH + c0 + 1];
            }
            hv32[(long)n * HVS32 + ii] = pack2(a0, a1);
        } else if (ii < HVS32) {
            hv32[(long)n * HVS32 + ii] = 0u;
        }
    }
}

__global__ void vninit_k(const float* __restrict__ vn0, float* __restrict__ vn) {
    int g = blockIdx.x, c = threadIdx.x;
    if (c < kH) vn[g * kH + c] = vn0[c];
}

// ---------------- gather + combine: one WAVE per node, u32 lanes, 4-wide unroll ----------------
__global__ __launch_bounds__(256) void gather_combine_k(
    const u32* __restrict__ hv32, const int* __restrict__ start_n,
    const int* __restrict__ perm, const float* __restrict__ eps, int l,
    u32* __restrict__ out32, float* __restrict__ stats) {
    int tid = threadIdx.x;
    int wave = tid >> 6, lane = tid & 63;
    int n = blockIdx.x * 4 + wave;
    int st = start_n[n], en = start_n[n + 1];
    int i0 = lane, i1 = lane + 64, i2 = lane + 128;
    bool p2 = (i2 < 150);
    float a0 = 0.f, b0 = 0.f, a1 = 0.f, b1 = 0.f, a2 = 0.f, b2 = 0.f;
    int e = st;
    for (; e + 4 <= en; e += 4) {
        const u32* rA = hv32 + (long)perm[e] * HVS32;
        const u32* rB = hv32 + (long)perm[e + 1] * HVS32;
        const u32* rC = hv32 + (long)perm[e + 2] * HVS32;
        const u32* rD = hv32 + (long)perm[e + 3] * HVS32;
        u32 vA0 = rA[i0], vA1 = rA[i1], vA2 = p2 ? rA[i2] : 0u;
        u32 vB0 = rB[i0], vB1 = rB[i1], vB2 = p2 ? rB[i2] : 0u;
        u32 vC0 = rC[i0], vC1 = rC[i1], vC2 = p2 ? rC[i2] : 0u;
        u32 vD0 = rD[i0], vD1 = rD[i1], vD2 = p2 ? rD[i2] : 0u;
        a0 += (blo(vA0) + blo(vB0)) + (blo(vC0) + blo(vD0));
        b0 += (bhi(vA0) + bhi(vB0)) + (bhi(vC0) + bhi(vD0));
        a1 += (blo(vA1) + blo(vB1)) + (blo(vC1) + blo(vD1));
        b1 += (bhi(vA1) + bhi(vB1)) + (bhi(vC1) + bhi(vD1));
        a2 += (blo(vA2) + blo(vB2)) + (blo(vC2) + blo(vD2));
        b2 += (bhi(vA2) + bhi(vB2)) + (bhi(vC2) + bhi(vD2));
    }
    for (; e + 2 <= en; e += 2) {
        const u32* rA = hv32 + (long)perm[e] * HVS32;
        const u32* rB = hv32 + (long)perm[e + 1] * HVS32;
        u32 vA0 = rA[i0], vA1 = rA[i1], vA2 = p2 ? rA[i2] : 0u;
        u32 vB0 = rB[i0], vB1 = rB[i1], vB2 = p2 ? rB[i2] : 0u;
        a0 += blo(vA0) + blo(vB0); b0 += bhi(vA0) + bhi(vB0);
        a1 += blo(vA1) + blo(vB1); b1 += bhi(vA1) + bhi(vB1);
        a2 += blo(vA2) + blo(vB2); b2 += bhi(vA2) + bhi(vB2);
    }
    if (e < en) {
        const u32* rA = hv32 + (long)perm[e] * HVS32;
        u32 vA0 = rA[i0], vA1 = rA[i1], vA2 = p2 ? rA[i2] : 0u;
        a0 += blo(vA0); b0 += bhi(vA0);
        a1 += blo(vA1); b1 += bhi(vA1);
        a2 += blo(vA2); b2 += bhi(vA2);
    }
    const u32* self = hv32 + (long)n * HVS32;
    float ep = 1.f + eps[l];
    u32 s0 = self[i0], s1 = self[i1];
    u32* o = out32 + (long)n * HVS32;
    o[i0] = pack2(ep * blo(s0) + a0, ep * bhi(s0) + b0);
    o[i1] = pack2(ep * blo(s1) + a1, ep * bhi(s1) + b1);
    if (p2) {
        u32 s2 = self[i2];
        o[i2] = pack2(ep * blo(s2) + a2, ep * bhi(s2) + b2);
    } else if (i2 < HVS32) {
        o[i2] = 0u;
    }
    int gz = blockIdx.x * 256 + tid;
    if (gz < 2 * kH) stats[gz] = 0.f;
}

// ---------------- vt (wave per graph, vectorized): vt[g] = sum_rows hvbf + vn_cur[g] ----------------
__global__ __launch_bounds__(256) void vt_fin_k(
    const u32* __restrict__ hv32, const float* __restrict__ vncur,
    const int* __restrict__ counts, const int* __restrict__ starts,
    u32* __restrict__ vt32) {
    int tid = threadIdx.x, wave = tid >> 6, lane = tid & 63;
    int g = blockIdx.x * 4 + wave;
    int cnt = counts[g], st = starts[g];
    int i0 = lane, i1 = lane + 64, i2 = lane + 128;
    bool p2 = (i2 < 150);
    float a0 = 0.f, b0 = 0.f, a1 = 0.f, b1 = 0.f, a2 = 0.f, b2 = 0.f;
    int i = 0;
    for (; i + 4 <= cnt; i += 4) {
        const u32* rA = hv32 + (long)(st + i) * HVS32;
        const u32* rB = hv32 + (long)(st + i + 1) * HVS32;
        const u32* rC = hv32 + (long)(st + i + 2) * HVS32;
        const u32* rD = hv32 + (long)(st + i + 3) * HVS32;
        u32 vA0 = rA[i0], vA1 = rA[i1], vA2 = p2 ? rA[i2] : 0u;
        u32 vB0 = rB[i0], vB1 = rB[i1], vB2 = p2 ? rB[i2] : 0u;
        u32 vC0 = rC[i0], vC1 = rC[i1], vC2 = p2 ? rC[i2] : 0u;
        u32 vD0 = rD[i0], vD1 = rD[i1], vD2 = p2 ? rD[i2] : 0u;
        a0 += (blo(vA0) + blo(vB0)) + (blo(vC0) + blo(vD0));
        b0 += (bhi(vA0) + bhi(vB0)) + (bhi(vC0) + bhi(vD0));
        a1 += (blo(vA1) + blo(vB1)) + (blo(vC1) + blo(vD1));
        b1 += (bhi(vA1) + bhi(vB1)) + (bhi(vC1) + bhi(vD1));
        a2 += (blo(vA2) + blo(vB2)) + (blo(vC2) + blo(vD2));
        b2 += (bhi(vA2) + bhi(vB2)) + (bhi(vC2) + bhi(vD2));
    }
    for (; i < cnt; i++) {
        const u32* rA = hv32 + (long)(st + i) * HVS32;
        u32 vA0 = rA[i0], vA1 = rA[i1], vA2 = p2 ? rA[i2] : 0u;
        a0 += blo(vA0); b0 += bhi(vA0);
        a1 += blo(vA1); b1 += bhi(vA1);
        a2 += blo(vA2); b2 += bhi(vA2);
    }
    const float* vg = vncur + g * kH;
    vt32[(long)g * HVS32 + i0] = pack2(a0 + vg[2 * i0], b0 + vg[2 * i0 + 1]);
    vt32[(long)g * HVS32 + i1] = pack2(a1 + vg[2 * i1], b1 + vg[2 * i1 + 1]);
    if (p2) vt32[(long)g * HVS32 + i2] = pack2(a2 + vg[2 * i2], b2 + vg[2 * i2 + 1]);
    else if (i2 < HVS32) vt32[(long)g * HVS32 + i2] = 0u;
}

// ---------------- GEMM: 128x128 tile, BK=64, global_load_lds + XOR-swizzled LDS ----------------
template<int ACT, int OUT_BF16, int BN_STATS>
__global__ __launch_bounds__(256) void gemm_k(
    const u16* __restrict__ A, const u16* __restrict__ Wt,
    const float* __restrict__ bias, void* __restrict__ out,
    float* __restrict__ stats,
    int KP, int NN, int out_stride, int store_cols) {
    __shared__ __align__(16) u16 lA[128 * 64];
    __shared__ __align__(16) u16 lB[128 * 64];
    __shared__ float sred[128][2];

    const int tid = threadIdx.x;
    const int lane = tid & 63;
    const int wave = tid >> 6;
    const int l16 = lane & 15;
    const int quad = lane >> 4;
    const int wm = (wave & 1) * 64;
    const int wn = (wave >> 1) * 64;
    const long tm = (long)blockIdx.x * 128;
    const int tn = blockIdx.y * 128;

    const int srow = lane >> 3;
    const int sch = (lane & 7) ^ srow;

    f32x4_t acc[4][4];
    #pragma unroll
    for (int i = 0; i < 4; i++)
        #pragma unroll
        for (int j = 0; j < 4; j++) acc[i][j] = (f32x4_t){0.f, 0.f, 0.f, 0.f};

    for (int k0 = 0; k0 < KP; k0 += 64) {
        __syncthreads();
        #pragma unroll
        for (int j = 0; j < 4; j++) {
            int rb = wave * 32 + j * 8;
            int r = rb + srow;
            gld16(A + (tm + r) * KP + k0 + sch * 8, &lA[rb * 64]);
            gld16(Wt + (long)(tn + r) * KP + k0 + sch * 8, &lB[rb * 64]);
        }
        __syncthreads();
        #pragma unroll
        for (int ks = 0; ks < 2; ks++) {
            bf16x8_t af[4], bfr[4];
            #pragma unroll
            for (int mt = 0; mt < 4; mt++) {
                int row = wm + mt * 16 + l16;
                int phys = (ks * 4 + quad) ^ (l16 & 7);
                af[mt] = *(const bf16x8_t*)&lA[row * 64 + phys * 8];
            }
            #pragma unroll
            for (int nt = 0; nt < 4; nt++) {
                int row = wn + nt * 16 + l16;
                int phys = (ks * 4 + quad) ^ (l16 & 7);
                bfr[nt] = *(const bf16x8_t*)&lB[row * 64 + phys * 8];
            }
            #pragma unroll
            for (int mt = 0; mt < 4; mt++)
                #pragma unroll
                for (int nt = 0; nt < 4; nt++)
                    acc[mt][nt] = __builtin_amdgcn_mfma_f32_16x16x32_bf16(af[mt], bfr[nt], acc[mt][nt], 0, 0, 0);
        }
    }

    if (BN_STATS) {
        if (tid < 128) { sred[tid][0] = 0.f; sred[tid][1] = 0.f; }
    }
    __syncthreads();

    #pragma unroll
    for (int nt = 0; nt < 4; nt++) {
        int col = tn + wn + nt * 16 + l16;
        float bv = (col < NN) ? bias[col] : 0.f;
        float s = 0.f, s2 = 0.f;
        #pragma unroll
        for (int mt = 0; mt < 4; mt++) {
            #pragma unroll
            for (int r = 0; r < 4; r++) {
                long row = tm + wm + mt * 16 + quad * 4 + r;
                float v = acc[mt][nt][r] + bv;
                if (ACT) v = fmaxf(v, 0.f);
                float sv = (col < NN) ? v : 0.f;
                if (col < store_cols) {
                    if (OUT_BF16) ((u16*)out)[row * out_stride + col] = f2bf(sv);
                    else          ((float*)out)[row * out_stride + col] = sv;
                }
                s += sv; s2 += sv * sv;
            }
        }
        if (BN_STATS) {
            atomicAdd(&sred[wn + nt * 16 + l16][0], s);
            atomicAdd(&sred[wn + nt * 16 + l16][1], s2);
        }
    }
    if (BN_STATS) {
        __syncthreads();
        if (tid < 128) {
            int col = tn + tid;
            if (col < NN) {
                atomicAdd(&stats[col], sred[tid][0]);
                atomicAdd(&stats[NN + col], sred[tid][1]);
            }
        }
    }
}

// ---------------- GEMM64: 128x64 tile; OUT_MODE: 0=f32, 1=bf16, 2=vn_nxt = vn_cur + relu(v) ----------------
template<int ACT, int OUT_MODE, int BN_STATS>
__global__ __launch_bounds__(256) void gemm64_k(
    const u16* __restrict__ A, const u16* __restrict__ Wt,
    const float* __restrict__ bias, void* __restrict__ out,
    float* __restrict__ stats, const float* __restrict__ vnacc,
    int KP, int NN, int out_stride, int store_cols) {
    __shared__ __align__(16) u16 lA[128 * 64];
    __shared__ __align__(16) u16 lB[64 * 64];
    __shared__ float sred[64][2];

    const int tid = threadIdx.x;
    const int lane = tid & 63;
    const int wave = tid >> 6;
    const int l16 = lane & 15;
    const int quad = lane >> 4;
    const int wm = (wave & 1) * 64;
    const int wn = (wave >> 1) * 32;
    const long tm = (long)blockIdx.x * 128;
    const int tn = blockIdx.y * 64;

    const int srow = lane >> 3;
    const int sch = (lane & 7) ^ srow;

    f32x4_t acc[4][2];
    #pragma unroll
    for (int i = 0; i < 4; i++)
        #pragma unroll
        for (int j = 0; j < 2; j++) acc[i][j] = (f32x4_t){0.f, 0.f, 0.f, 0.f};

    for (int k0 = 0; k0 < KP; k0 += 64) {
        __syncthreads();
        #pragma unroll
        for (int j = 0; j < 4; j++) {
            int rb = wave * 32 + j * 8;
            gld16(A + (tm + rb + srow) * KP + k0 + sch * 8, &lA[rb * 64]);
        }
        #pragma unroll
        for (int j = 0; j < 2; j++) {
            int rb = wave * 16 + j * 8;
            gld16(Wt + (long)(tn + rb + srow) * KP + k0 + sch * 8, &lB[rb * 64]);
        }
        __syncthreads();
        #pragma unroll
        for (int ks = 0; ks < 2; ks++) {
            bf16x8_t af[4], bfr[2];
            #pragma unroll
            for (int mt = 0; mt < 4; mt++) {
                int row = wm + mt * 16 + l16;
                int phys = (ks * 4 + quad) ^ (l16 & 7);
                af[mt] = *(const bf16x8_t*)&lA[row * 64 + phys * 8];
            }
            #pragma unroll
            for (int nt = 0; nt < 2; nt++) {
                int row = wn + nt * 16 + l16;
                int phys = (ks * 4 + quad) ^ (l16 & 7);
                bfr[nt] = *(const bf16x8_t*)&lB[row * 64 + phys * 8];
            }
            #pragma unroll
            for (int mt = 0; mt < 4; mt++)
                #pragma unroll
                for (int nt = 0; nt < 2; nt++)
                    acc[mt][nt] = __builtin_amdgcn_mfma_f32_16x16x32_bf16(af[mt], bfr[nt], acc[mt][nt], 0, 0, 0);
        }
    }

    if (BN_STATS) {
        if (tid < 64) { sred[tid][0] = 0.f; sred[tid][1] = 0.f; }
    }
    __syncthreads();

    #pragma unroll
    for (int nt = 0; nt < 2; nt++) {
        int col = tn + wn + nt * 16 + l16;
        float bv = (col < NN) ? bias[col] : 0.f;
        float s = 0.f, s2 = 0.f;
        #pragma unroll
        for (int mt = 0; mt < 4; mt++) {
            #pragma unroll
            for (int r = 0; r < 4; r++) {
                long row = tm + wm + mt * 16 + quad * 4 + r;
                float v = acc[mt][nt][r] + bv;
                if (ACT) v = fmaxf(v, 0.f);
                float sv = (col < NN) ? v : 0.f;
                if (col < store_cols) {
                    if (OUT_MODE == 1) ((u16*)out)[row * out_stride + col] = f2bf(sv);
                    else if (OUT_MODE == 2)
                        ((float*)out)[row * out_stride + col] =
                            vnacc[row * out_stride + col] + fmaxf(v, 0.f);
                    else ((float*)out)[row * out_stride + col] = sv;
                }
                s += sv; s2 += sv * sv;
            }
        }
        if (BN_STATS) {
            atomicAdd(&sred[wn + nt * 16 + l16][0], s);
            atomicAdd(&sred[wn + nt * 16 + l16][1], s2);
        }
    }
    if (BN_STATS) {
        __syncthreads();
        if (tid < 64) {
            int col = tn + tid;
            if (col < NN) {
                atomicAdd(&stats[col], sred[tid][0]);
                atomicAdd(&stats[NN + col], sred[tid][1]);
            }
        }
    }
}

// ---------------- BN-apply + (relu) + residual; h reconstructed from hvbf - vn_cur ----------------
template<int RELU>
__global__ __launch_bounds__(256) void resid_k(
    u32* __restrict__ hvb32, const u32* __restrict__ z32,
    const float* __restrict__ stats,
    const float* __restrict__ scale, const float* __restrict__ bias, int l,
    const int* __restrict__ batch,
    const float* __restrict__ vncur, const float* __restrict__ vnnxt) {
    int tid = threadIdx.x;
    int wave = tid >> 6, lane = tid & 63;
    int n = blockIdx.x * 4 + wave;
    int g = batch[n];
    #pragma unroll
    for (int p = 0; p < 3; p++) {
        int ii = lane + p * 64;
        if (ii >= 150) break;
        int c0 = 2 * ii;
        float m0 = stats[c0] * (1.f / (float)kN), m1 = stats[c0 + 1] * (1.f / (float)kN);
        float v0 = fmaxf(stats[kH + c0] * (1.f / (float)kN) - m0 * m0, 0.f);
        float v1 = fmaxf(stats[kH + c0 + 1] * (1.f / (float)kN) - m1 * m1, 0.f);
        float a0 = scale[l * kH + c0] * rsqrtf(v0 + 1e-5f);
        float a1 = scale[l * kH + c0 + 1] * rsqrtf(v1 + 1e-5f);
        float d0 = bias[l * kH + c0] - m0 * a0;
        float d1 = bias[l * kH + c0 + 1] - m1 * a1;
        u32 zz = z32[(long)n * HVS32 + ii];
        u32 ho = hvb32[(long)n * HVS32 + ii];
        float2 vc = *(const float2*)(vncur + g * kH + c0);
        float2 vx = *(const float2*)(vnnxt + g * kH + c0);
        float t0 = blo(zz) * a0 + d0;
        float t1 = bhi(zz) * a1 + d1;
        if (RELU) { t0 = fmaxf(t0, 0.f); t1 = fmaxf(t1, 0.f); }
        float h0 = (blo(ho) - vc.x) + t0;
        float h1 = (bhi(ho) - vc.y) + t1;
        hvb32[(long)n * HVS32 + ii] = pack2(h0 + vx.x, h1 + vx.y);
    }
}

// ---------------- pooled mean (wave per graph): (sum hvbf - cnt*vn_last)/cnt -> hrep[:,0:300] ----------------
__global__ __launch_bounds__(256) void pooled_k(
    const u32* __restrict__ hv32, const float* __restrict__ vnlast,
    const int* __restrict__ counts, const int* __restrict__ starts,
    u32* __restrict__ hrep32) {
    int tid = threadIdx.x, wave = tid >> 6, lane = tid & 63;
    int g = blockIdx.x * 4 + wave;
    int cnt = counts[g], st = starts[g];
    int i0 = lane, i1 = lane + 64, i2 = lane + 128;
    bool p2 = (i2 < 150);
    float a0 = 0.f, b0 = 0.f, a1 = 0.f, b1 = 0.f, a2 = 0.f, b2 = 0.f;
    int i = 0;
    for (; i + 4 <= cnt; i += 4) {
        const u32* rA = hv32 + (long)(st + i) * HVS32;
        const u32* rB = hv32 + (long)(st + i + 1) * HVS32;
        const u32* rC = hv32 + (long)(st + i + 2) * HVS32;
        const u32* rD = hv32 + (long)(st + i + 3) * HVS32;
        u32 vA0 = rA[i0], vA1 = rA[i1], vA2 = p2 ? rA[i2] : 0u;
        u32 vB0 = rB[i0], vB1 = rB[i1], vB2 = p2 ? rB[i2] : 0u;
        u32 vC0 = rC[i0], vC1 = rC[i1], vC2 = p2 ? rC[i2] : 0u;
        u32 vD0 = rD[i0], vD1 = rD[i1], vD2 = p2 ? rD[i2] : 0u;
        a0 += (blo(vA0) + blo(vB0)) + (blo(vC0) + blo(vD0));
        b0 += (bhi(vA0) + bhi(vB0)) + (bhi(vC0) + bhi(vD0));
        a1 += (blo(vA1) + blo(vB1)) + (blo(vC1) + blo(vD1));
        b1 += (bhi(vA1) + bhi(vB1)) + (bhi(vC1) + bhi(vD1));
        a2 += (blo(vA2) + blo(vB2)) + (blo(vC2) + blo(vD2));
        b2 += (bhi(vA2) + bhi(vB2)) + (bhi(vC2) + bhi(vD2));
    }
    for (; i < cnt; i++) {
        const u32* rA = hv32 + (long)(st + i) * HVS32;
        u32 vA0 = rA[i0], vA1 = rA[i1], vA2 = p2 ? rA[i2] : 0u;
        a0 += blo(vA0); b0 += bhi(vA0);
        a1 += blo(vA1); b1 += bhi(vA1);
        a2 += blo(vA2); b2 += bhi(vA2);
    }
    float fc = (float)cnt;
    float inv = 1.f / (float)(cnt > 0 ? cnt : 1);
    const float* vg = vnlast + g * kH;
    hrep32[(long)g * 768 + i0] = pack2((a0 - fc * vg[2 * i0]) * inv, (b0 - fc * vg[2 * i0 + 1]) * inv);
    hrep32[(long)g * 768 + i1] = pack2((a1 - fc * vg[2 * i1]) * inv, (b1 - fc * vg[2 * i1 + 1]) * inv);
    if (p2)
        hrep32[(long)g * 768 + i2] = pack2((a2 - fc * vg[2 * i2]) * inv, (b2 - fc * vg[2 * i2 + 1]) * inv);
}

// ---------------- h_rep cols [300,1536): id_pool | morgan | maccs | zero-pad ----------------
__global__ void hrep_rest_k(const float* __restrict__ morgan, const float* __restrict__ maccs,
                            const int* __restrict__ counts, u16* __restrict__ hrep) {
    long idx = (long)blockIdx.x * 256 + threadIdx.x;
    if (idx >= (long)kG * (KP_DG - kH)) return;
    int g = (int)(idx / (KP_DG - kH));
    int j = (int)(idx % (KP_DG - kH));
    int col = kH + j;
    u16 v;
    if (j < kF) {
        int c = counts[g];
        int q = (j < c) ? ((c - 1 - j) / kF + 1) : 0;
        v = f2bf((float)q / (float)(c > 0 ? c : 1));
    } else if (j < kF + 1024) {
        v = f2bf(morgan[(long)g * 1024 + (j - kF)]);
    } else if (j < kF + 1024 + 167) {
        v = f2bf(maccs[(long)g * 167 + (j - kF - 1024)]);
    } else {
        v = 0;
    }
    hrep[(long)g * KP_DG + col] = v;
}

// ---------------- final: out[g] = zp[g,:600] . Wp2 + bp2 ----------------
__global__ void final_k(const u16* __restrict__ zp, const float* __restrict__ Wp2,
                        const float* __restrict__ bp2, float* __restrict__ out) {
    int wave = threadIdx.x >> 6, lane = threadIdx.x & 63;
    int g = blockIdx.x * 4 + wave;
    float acc = 0.f;
    for (int c = lane; c < kH2; c += 64) acc += bf2f(zp[(long)g * KP_H2 + c]) * Wp2[c];
    #pragma unroll
    for (int off = 32; off; off >>= 1) acc += __shfl_down(acc, off);
    if (lane == 0) out[g] = acc + bp2[0];
}

extern "C" void kernel_launch(void* const* d_in, const int* in_sizes, int n_in,
                              void* d_out, int out_size, void* d_ws, size_t ws_size,
                              hipStream_t stream) {
    const float* x      = (const float*)d_in[0];
    const float* morgan = (const float*)d_in[1];
    const float* maccs  = (const float*)d_in[2];
    const int*   ei     = (const int*)d_in[3];
    const int*   batch  = (const int*)d_in[4];
    const float* W_emb  = (const float*)d_in[5];
    const float* b_emb  = (const float*)d_in[6];
    const float* gin_W1 = (const float*)d_in[7];
    const float* gin_b1 = (const float*)d_in[8];
    const float* gin_W2 = (const float*)d_in[9];
    const float* gin_b2 = (const float*)d_in[10];
    const float* bn_scale = (const float*)d_in[11];
    const float* bn_bias  = (const float*)d_in[12];
    const float* eps    = (const float*)d_in[13];
    const float* vn0    = (const float*)d_in[14];
    const float* vn_W1  = (const float*)d_in[15];
    const float* vn_b1  = (const float*)d_in[16];
    const float* vn_W2  = (const float*)d_in[17];
    const float* vn_b2  = (const float*)d_in[18];
    const float* Wp1    = (const float*)d_in[19];
    const float* bp1    = (const float*)d_in[20];
    const float* Wp2    = (const float*)d_in[21];
    const float* bp2    = (const float*)d_in[22];
    float* out = (float*)d_out;

    char* ws = (char*)d_ws;
    size_t off = 0;
    auto alloc = [&](size_t bytes) -> char* {
        char* p = ws + off;
        off += (bytes + 255) & ~(size_t)255;
        return p;
    };
    u16*   hvbf = (u16*)alloc((size_t)kN * HVS * 2);        // 41.9 MB  bf16(h + vn_cur[batch])
    u16*   hv   = (u16*)alloc((size_t)kN * KP_H * 2);       // 41.9 MB  gather out -> z2 (in place)
    u16*   z1   = (u16*)alloc((size_t)kN * KP_H2 * 2);      // 83.9 MB  full-M z1 (+ small overlays)
    float* vnA  = (float*)alloc((size_t)kG * kH * 4);       // 2.46 MB
    float* vnB  = (float*)alloc((size_t)kG * kH * 4);       // 2.46 MB
    int* counts = (int*)alloc(kG * 4);
    int* starts = (int*)alloc(kG * 4);
    float* stats = (float*)alloc(2 * kH * 4);
    int* cnt_n  = (int*)alloc((size_t)kN * 4);
    int* start_n = (int*)alloc((size_t)(kN + 1) * 4);
    int* fill_n = (int*)alloc((size_t)kN * 4);
    int* bsum   = (int*)alloc((kN / 1024) * 4);
    int* perm   = (int*)alloc((size_t)kE * 4);
    u16* Wt_g1 = (u16*)alloc((size_t)kL * NP_H2 * KP_H * 2);
    u16* Wt_g2 = (u16*)alloc((size_t)kL * NP_H * KP_H2 * 2);
    u16* Wt_v1 = (u16*)alloc((size_t)(kL - 1) * NP_H2 * KP_H * 2);
    u16* Wt_v2 = (u16*)alloc((size_t)(kL - 1) * NP_H * KP_H2 * 2);
    u16* Wt_p1 = (u16*)alloc((size_t)NP_H2 * KP_DG * 2);
    if (off > ws_size) return;  // ~184 MB required

    // z1-region overlays (disjoint lifetimes):
    u16* vt_in = z1;                                   // [2048,320] bf16 (pre node-G1)
    u16* z1v   = z1 + (size_t)4 * 1024 * 1024;         // [2048,640] bf16 (pre node-G1)
    u16* hrep  = z1;                                   // [2048,1536] bf16 (post layers)
    u16* zp    = z1 + (size_t)8 * 1024 * 1024;         // [2048,640] bf16 (post layers)
    float* vnb[2] = {vnA, vnB};

    // weight transposes
    {
        long t1 = (long)kL * NP_H2 * KP_H;
        transpose_k<<<dim3((unsigned)((t1 + 255) / 256)), 256, 0, stream>>>(gin_W1, Wt_g1, kH, kH2, NP_H2, KP_H, t1);
        long t2 = (long)kL * NP_H * KP_H2;
        transpose_k<<<dim3((unsigned)((t2 + 255) / 256)), 256, 0, stream>>>(gin_W2, Wt_g2, kH2, kH, NP_H, KP_H2, t2);
        long t3 = (long)(kL - 1) * NP_H2 * KP_H;
        transpose_k<<<dim3((unsigned)((t3 + 255) / 256)), 256, 0, stream>>>(vn_W1, Wt_v1, kH, kH2, NP_H2, KP_H, t3);
        long t4 = (long)(kL - 1) * NP_H * KP_H2;
        transpose_k<<<dim3((unsigned)((t4 + 255) / 256)), 256, 0, stream>>>(vn_W2, Wt_v2, kH2, kH, NP_H, KP_H2, t4);
        long t5 = (long)NP_H2 * KP_DG;
        transpose_k<<<dim3((unsigned)((t5 + 255) / 256)), 256, 0, stream>>>(Wp1, Wt_p1, kDG, kH2, NP_H2, KP_DG, t5);
    }

    // graph ranges + node CSR
    hipMemsetAsync(counts, 0, kG * 4, stream);
    hipMemsetAsync(cnt_n, 0, (size_t)kN * 4, stream);
    hipMemsetAsync(fill_n, 0, (size_t)kN * 4, stream);
    hist_g_k<<<kN / 256, 256, 0, stream>>>(batch, counts);
    scan_g_k<<<1, 1024, 0, stream>>>(counts, starts);
    hist_n_k<<<kE / 256, 256, 0, stream>>>(ei, cnt_n);
    scanA_k<<<kN / 1024, 1024, 0, stream>>>(cnt_n, start_n, bsum);
    scanB_k<<<1, 64, 0, stream>>>(bsum);
    scanC_k<<<kN / 1024, 1024, 0, stream>>>(start_n, bsum);
    fill_n_k<<<kE / 256, 256, 0, stream>>>(ei, start_n, fill_n, perm);

    embed_k<<<kN / 4, 256, 0, stream>>>(x, W_emb, b_emb, vn0, (u32*)hvbf);
    vninit_k<<<kG, 320, 0, stream>>>(vn0, vnA);

    for (int l = 0; l < kL; l++) {
        float* vcur = vnb[l & 1];
        float* vnxt = vnb[(l + 1) & 1];
        gather_combine_k<<<kN / 4, 256, 0, stream>>>(
            (const u32*)hvbf, start_n, perm, eps, l, (u32*)hv, stats);
        if (l < kL - 1) {
            vt_fin_k<<<kG / 4, 256, 0, stream>>>(
                (const u32*)hvbf, vcur, counts, starts, (u32*)vt_in);
            gemm_k<1, 1, 0><<<dim3(16, NP_H2 / 128), 256, 0, stream>>>(
                vt_in, Wt_v1 + (size_t)l * NP_H2 * KP_H, vn_b1 + l * kH2,
                z1v, nullptr, KP_H, kH2, KP_H2, KP_H2);
            gemm64_k<0, 2, 0><<<dim3(16, NP_H / 64), 256, 0, stream>>>(
                z1v, Wt_v2 + (size_t)l * NP_H * KP_H2, vn_b2 + l * kH,
                vnxt, nullptr, vcur, KP_H2, kH, kH, kH);
        }
        // node MLP, full-M (z1 84 MB)
        gemm_k<1, 1, 0><<<dim3(kN / 128, NP_H2 / 128), 256, 0, stream>>>(
            hv, Wt_g1 + (size_t)l * NP_H2 * KP_H, gin_b1 + l * kH2,
            z1, nullptr, KP_H, kH2, KP_H2, KP_H2);
        gemm64_k<0, 1, 1><<<dim3(kN / 128, NP_H / 64), 256, 0, stream>>>(
            z1, Wt_g2 + (size_t)l * NP_H * KP_H2, gin_b2 + l * kH,
            hv, stats, nullptr, KP_H2, kH, KP_H, KP_H);
        if (l < kL - 1)
            resid_k<1><<<kN / 4, 256, 0, stream>>>(
                (u32*)hvbf, (const u32*)hv, stats, bn_scale, bn_bias, l, batch, vcur, vnxt);
        else
            resid_k<0><<<kN / 4, 256, 0, stream>>>(
                (u32*)hvbf, (const u32*)hv, stats, bn_scale, bn_bias, l, batch, vcur, vcur);
    }

    // FIX (round 12 bug): last layer's vcur is vnb[(kL-1)&1] = vnb[0] — that is what
    // the final resid added into hvbf, so pooled must subtract THAT buffer.
    // (Old code used vnb[kL & 1] = vnb[1] = stale vn -> absmax 3.7.)
    float* vnlast = vnb[(kL - 1) & 1];
    pooled_k<<<kG / 4, 256, 0, stream>>>(
        (const u32*)hvbf, vnlast, counts, starts, (u32*)hrep);
    {
        long tr = (long)kG * (KP_DG - kH);
        hrep_rest_k<<<dim3((unsigned)((tr + 255) / 256)), 256, 0, stream>>>(morgan, maccs, counts, hrep);
    }
    gemm_k<1, 1, 0><<<dim3(16, NP_H2 / 128), 256, 0, stream>>>(
        hrep, Wt_p1, bp1, zp, nullptr, KP_DG, kH2, KP_H2, KP_H2);
    final_k<<<kG / 4, 256, 0, stream>>>(zp, Wp2, bp2, out);
}